// Round 1
// baseline (1210.623 us; speedup 1.0000x reference)
//
#include <hip/hip_runtime.h>
#include <math.h>

#define T_LEN 8192
#define D_IN  1024
#define NH    16
#define NPAD  4224   // 32 (i/f all heads) + 16*256 (k,q,v,o per head) = 4128, padded to 33*128
#define NCH   128    // number of 64-step chunks

// ---- workspace layout (float offsets) ----
static const size_t OFF_WP   = 0;                                  // [NPAD][1024]
static const size_t OFF_BIAS = OFF_WP + (size_t)NPAD * D_IN;       // [NPAD]
static const size_t OFF_P    = OFF_BIAS + NPAD;                    // [T][NPAD]
static const size_t OFF_M    = OFF_P + (size_t)T_LEN * NPAD;       // [T][16]
static const size_t OFF_DC   = OFF_M + (size_t)T_LEN * NH;         // [NCH][16][64][64]
static const size_t OFF_DN   = OFF_DC + (size_t)NCH * NH * 64 * 64;// [NCH][16][64]
static const size_t OFF_DL   = OFF_DN + (size_t)NCH * NH * 64;     // [NCH][16]
// total = 47,585,408 floats = ~181.5 MiB

// -------------------------------------------------------------------------
// Pack weights into W[4224][1024]; row order per head h (base 32+256h):
//   [0..64) k rows (pre-scaled by 1/8), [64..128) q, [128..192) v, [192..256) o
// rows [0..32): i/f interleaved for all heads (n=2h -> i, 2h+1 -> f).
// bias[n] assembled to be added in GEMM epilogue.
// -------------------------------------------------------------------------
__global__ __launch_bounds__(256) void pack_w(
    const float* __restrict__ ifw, const float* __restrict__ ow,
    const float* __restrict__ kqw, const float* __restrict__ vw,
    const float* __restrict__ ifb, const float* __restrict__ ob,
    const float* __restrict__ kvqb, float* __restrict__ Wp, float* __restrict__ bias) {
  int idx = blockIdx.x * 256 + threadIdx.x;
  int n = idx >> 10, d = idx & 1023;
  float w = 0.f, b = 0.f;
  if (n < 32) {
    int h = n >> 1, t = n & 1;
    w = ifw[(h * 2 + t) * D_IN + d];
    b = ifb[h * 2 + t];
  } else if (n < 4128) {
    int r = n - 32;
    int h = r >> 8, j = r & 255;
    if (j < 64)       { w = kqw[(h * 128 + j) * D_IN + d] * 0.125f; b = kvqb[(h * 3 + 0) * 64 + j]; }
    else if (j < 128) { w = kqw[(h * 128 + j) * D_IN + d];          b = kvqb[(h * 3 + 2) * 64 + (j - 64)]; }
    else if (j < 192) { w = vw[(h * 64 + (j - 128)) * D_IN + d];    b = kvqb[(h * 3 + 1) * 64 + (j - 128)]; }
    else              { w = ow[(h * 64 + (j - 192)) * D_IN + d];    b = ob[h * 64 + (j - 192)]; }
  }
  Wp[(size_t)n * D_IN + d] = w;
  if (d == 0) bias[n] = b;
}

// -------------------------------------------------------------------------
// fp32 GEMM: P[8192][4224] = X[8192][1024] * Wp[4224][1024]^T + bias
// 128x128 tile, 256 threads, 8x8 per thread, K-step 16.
// -------------------------------------------------------------------------
__global__ __launch_bounds__(256) void gemm_f32(
    const float* __restrict__ X, const float* __restrict__ Wp,
    const float* __restrict__ bias, float* __restrict__ P) {
  __shared__ float As[16][132];
  __shared__ float Bs[16][132];
  int tid = threadIdx.x;
  int m0 = blockIdx.y << 7, n0 = blockIdx.x << 7;
  int lm = tid >> 1, lk = (tid & 1) << 3;
  int ty = tid >> 4, tx = tid & 15;
  float acc[8][8];
#pragma unroll
  for (int i = 0; i < 8; ++i)
#pragma unroll
    for (int j = 0; j < 8; ++j) acc[i][j] = 0.f;
  const float* ap = X + (size_t)(m0 + lm) * D_IN + lk;
  const float* bp = Wp + (size_t)(n0 + lm) * D_IN + lk;
  for (int k0 = 0; k0 < D_IN; k0 += 16) {
    float4 a0 = *(const float4*)(ap + k0);
    float4 a1 = *(const float4*)(ap + k0 + 4);
    float4 b0 = *(const float4*)(bp + k0);
    float4 b1 = *(const float4*)(bp + k0 + 4);
    __syncthreads();
    As[lk + 0][lm] = a0.x; As[lk + 1][lm] = a0.y; As[lk + 2][lm] = a0.z; As[lk + 3][lm] = a0.w;
    As[lk + 4][lm] = a1.x; As[lk + 5][lm] = a1.y; As[lk + 6][lm] = a1.z; As[lk + 7][lm] = a1.w;
    Bs[lk + 0][lm] = b0.x; Bs[lk + 1][lm] = b0.y; Bs[lk + 2][lm] = b0.z; Bs[lk + 3][lm] = b0.w;
    Bs[lk + 4][lm] = b1.x; Bs[lk + 5][lm] = b1.y; Bs[lk + 6][lm] = b1.z; Bs[lk + 7][lm] = b1.w;
    __syncthreads();
#pragma unroll
    for (int kk = 0; kk < 16; ++kk) {
      float a[8], b[8];
      *(float4*)&a[0] = *(const float4*)&As[kk][ty << 3];
      *(float4*)&a[4] = *(const float4*)&As[kk][(ty << 3) + 4];
      *(float4*)&b[0] = *(const float4*)&Bs[kk][tx << 3];
      *(float4*)&b[4] = *(const float4*)&Bs[kk][(tx << 3) + 4];
#pragma unroll
      for (int i = 0; i < 8; ++i)
#pragma unroll
        for (int j = 0; j < 8; ++j) acc[i][j] = fmaf(a[i], b[j], acc[i][j]);
    }
  }
#pragma unroll
  for (int i = 0; i < 8; ++i) {
    int m = m0 + (ty << 3) + i;
#pragma unroll
    for (int jq = 0; jq < 8; jq += 4) {
      int n = n0 + (tx << 3) + jq;
      float4 bb = *(const float4*)(bias + n);
      float4 st;
      st.x = acc[i][jq + 0] + bb.x;
      st.y = acc[i][jq + 1] + bb.y;
      st.z = acc[i][jq + 2] + bb.z;
      st.w = acc[i][jq + 3] + bb.w;
      *(float4*)(P + (size_t)m * NPAD + n) = st;
    }
  }
}

// -------------------------------------------------------------------------
// m-scan: m_t = max(f_t + m_{t-1}, i_t), m_{-1}=0.  16 blocks (1 head each),
// 64 threads; LDS-staged chunks, all lanes redundantly walk the recurrence.
// -------------------------------------------------------------------------
__global__ __launch_bounds__(64) void mscan(const float* __restrict__ P, float* __restrict__ M) {
  int h = blockIdx.x, lane = threadIdx.x;
  __shared__ float sI[64], sF[64];
  float m = 0.f;
  float2 v0 = *(const float2*)(P + (size_t)lane * NPAD + 2 * h);
  float ri = v0.x, rf = v0.y;
  for (int c = 0; c < NCH; ++c) {
    __syncthreads();
    sI[lane] = ri; sF[lane] = rf;
    __syncthreads();
    if (c < NCH - 1) {
      int t = (c + 1) * 64 + lane;
      float2 v = *(const float2*)(P + (size_t)t * NPAD + 2 * h);
      ri = v.x; rf = v.y;
    }
    float myM = 0.f;
#pragma unroll 8
    for (int u = 0; u < 64; ++u) {
      m = fmaxf(sF[u] + m, sI[u]);
      myM = (u == lane) ? m : myM;
    }
    M[(size_t)(c * 64 + lane) * NH + h] = myM;
  }
}

// -------------------------------------------------------------------------
// D1: per (chunk,head): DC = sum_s g_s v_s k_s^T,  DN = sum_s g_s k_s,
//     DL = chunk decay,  with g_s = exp(cumF_L - cumF_s + i_s - m_L).
// -------------------------------------------------------------------------
__global__ __launch_bounds__(256) void d1_dc(
    const float* __restrict__ P, const float* __restrict__ M,
    float* __restrict__ DC, float* __restrict__ DN, float* __restrict__ DL) {
  int c = blockIdx.x >> 4, h = blockIdx.x & 15;
  int t0 = c << 6, hb = 32 + (h << 8);
  int tid = threadIdx.x;
  __shared__ float Kl[64][65];
  __shared__ float Vl[64][65];
  __shared__ float gl[64];
#pragma unroll
  for (int i = 0; i < 4; ++i) {
    int fq = (i << 8) + tid;            // float4 index 0..1023
    int s = fq >> 4, b4 = (fq & 15) << 2;
    const float* row = P + (size_t)(t0 + s) * NPAD + hb;
    float4 kv = *(const float4*)(row + b4);
    float4 vv = *(const float4*)(row + 128 + b4);
    Kl[s][b4 + 0] = kv.x; Kl[s][b4 + 1] = kv.y; Kl[s][b4 + 2] = kv.z; Kl[s][b4 + 3] = kv.w;
    Vl[s][b4 + 0] = vv.x; Vl[s][b4 + 1] = vv.y; Vl[s][b4 + 2] = vv.z; Vl[s][b4 + 3] = vv.w;
  }
  if (tid < 64) {
    float2 iff = *(const float2*)(P + (size_t)(t0 + tid) * NPAD + (h << 1));
    float iv = iff.x, fv = iff.y;
    float cs = fv;
#pragma unroll
    for (int dd = 1; dd < 64; dd <<= 1) {
      float o = __shfl_up(cs, dd, 64);
      cs += (tid >= dd) ? o : 0.f;
    }
    float cumL = __shfl(cs, 63, 64);
    float mL = M[(size_t)(t0 + 63) * NH + h];
    gl[tid] = __expf(cumL - cs + iv - mL);
    if (tid == 0) {
      float mstart = (c > 0) ? M[(size_t)(t0 - 1) * NH + h] : 0.f;
      DL[(c << 4) + h] = __expf(mstart + cumL - mL);
    }
  }
  __syncthreads();
  if (tid < 64) {
    float acc = 0.f;
#pragma unroll
    for (int s = 0; s < 64; ++s) acc = fmaf(gl[s], Kl[s][tid], acc);
    DN[((size_t)(c << 4) + h) * 64 + tid] = acc;
  }
  int a = tid & 63, bq = tid >> 6;
  float acc[16];
#pragma unroll
  for (int j = 0; j < 16; ++j) acc[j] = 0.f;
  for (int s = 0; s < 64; ++s) {
    float gv = gl[s] * Vl[s][a];
#pragma unroll
    for (int j = 0; j < 16; ++j) acc[j] = fmaf(gv, Kl[s][(bq << 4) + j], acc[j]);
  }
  size_t base = (((size_t)(c << 4) + h) << 12) + ((size_t)a << 6) + (bq << 4);
#pragma unroll
  for (int j4 = 0; j4 < 16; j4 += 4) {
    float4 st; st.x = acc[j4]; st.y = acc[j4 + 1]; st.z = acc[j4 + 2]; st.w = acc[j4 + 3];
    *(float4*)(DC + base + j4) = st;
  }
}

// -------------------------------------------------------------------------
// D2: in-place weighted prefix over chunks:
//   carry(0)=0; iterate c: v=buf[c]; buf[c]=carry; carry = DL[c]*carry + v.
// blocks 0..255: DC elements (16 heads x 4096).  blocks 256..259: DN.
// -------------------------------------------------------------------------
__global__ __launch_bounds__(256) void d2_prefix(
    float* __restrict__ DC, float* __restrict__ DN, const float* __restrict__ DL) {
  int bid = blockIdx.x, tid = threadIdx.x;
  if (bid < 256) {
    int e = (bid << 8) + tid;          // 0..65535
    int h = e >> 12, pos = e & 4095;
    float carry = 0.f;
    size_t idx = ((size_t)h << 12) + pos;
    float v = DC[idx];
    for (int c = 0; c < NCH; ++c) {
      float dl = DL[(c << 4) + h];
      float vn = (c < NCH - 1) ? DC[idx + 65536] : 0.f;
      DC[idx] = carry;
      carry = fmaf(dl, carry, v);
      v = vn;
      idx += 65536;
    }
  } else {
    int e = ((bid - 256) << 8) + tid;  // 0..1023
    int h = e >> 6, b = e & 63;
    float carry = 0.f;
    size_t idx = ((size_t)h << 6) + b;
    float v = DN[idx];
    for (int c = 0; c < NCH; ++c) {
      float dl = DL[(c << 4) + h];
      float vn = (c < NCH - 1) ? DN[idx + 1024] : 0.f;
      DN[idx] = carry;
      carry = fmaf(dl, carry, v);
      v = vn;
      idx += 1024;
    }
  }
}

// -------------------------------------------------------------------------
// D3: per (chunk,head) outputs.
//  S=QK^T; P=W.*S (W = exp(cf[t]-cf[s]+i[s]-m[t]), s<=t); den=rowsum(P);
//  h = d_t*(Cstart q_t) + P V;  denom = d_t*(nstart.q_t)+den;
//  out = sigmoid(o) * h / max(|denom|,1).
// -------------------------------------------------------------------------
__global__ __launch_bounds__(256) void d3_out(
    const float* __restrict__ P, const float* __restrict__ M,
    const float* __restrict__ CS, const float* __restrict__ NS,
    float* __restrict__ out) {
  int c = blockIdx.x >> 4, h = blockIdx.x & 15;
  int t0 = c << 6, hb = 32 + (h << 8);
  int tid = threadIdx.x;
  __shared__ float KP[64][65];   // K, later overwritten with P=W.*S
  __shared__ float Ql[64][65];
  __shared__ float Vl[64][65];
  __shared__ float Cst[64][65];  // Cstart[a][b]
  __shared__ float cf[64], il[64], ml[64], dl[64], nq[64], den[64], nsl[64];
#pragma unroll
  for (int i = 0; i < 4; ++i) {
    int fq = (i << 8) + tid;
    int s = fq >> 4, b4 = (fq & 15) << 2;
    const float* row = P + (size_t)(t0 + s) * NPAD + hb;
    float4 kv = *(const float4*)(row + b4);
    float4 qv = *(const float4*)(row + 64 + b4);
    float4 vv = *(const float4*)(row + 128 + b4);
    float4 cv = *(const float4*)(CS + ((((size_t)(c << 4)) + h) << 12) + ((size_t)s << 6) + b4);
    KP[s][b4 + 0] = kv.x; KP[s][b4 + 1] = kv.y; KP[s][b4 + 2] = kv.z; KP[s][b4 + 3] = kv.w;
    Ql[s][b4 + 0] = qv.x; Ql[s][b4 + 1] = qv.y; Ql[s][b4 + 2] = qv.z; Ql[s][b4 + 3] = qv.w;
    Vl[s][b4 + 0] = vv.x; Vl[s][b4 + 1] = vv.y; Vl[s][b4 + 2] = vv.z; Vl[s][b4 + 3] = vv.w;
    Cst[s][b4 + 0] = cv.x; Cst[s][b4 + 1] = cv.y; Cst[s][b4 + 2] = cv.z; Cst[s][b4 + 3] = cv.w;
  }
  float iv = 0.f, mt = 0.f, cs = 0.f;
  if (tid < 64) {
    float2 iff = *(const float2*)(P + (size_t)(t0 + tid) * NPAD + (h << 1));
    iv = iff.x;
    float fv = iff.y;
    mt = M[(size_t)(t0 + tid) * NH + h];
    nsl[tid] = NS[((size_t)(c << 4) + h) * 64 + tid];
    cs = fv;
#pragma unroll
    for (int dd = 1; dd < 64; dd <<= 1) {
      float o = __shfl_up(cs, dd, 64);
      cs += (tid >= dd) ? o : 0.f;
    }
  }
  __syncthreads();
  if (tid < 64) {
    cf[tid] = cs; il[tid] = iv; ml[tid] = mt;
    float mstart = (c > 0) ? M[(size_t)(t0 - 1) * NH + h] : 0.f;
    dl[tid] = __expf(mstart + cs - mt);
    float acc = 0.f;
#pragma unroll
    for (int b = 0; b < 64; ++b) acc = fmaf(nsl[b], Ql[tid][b], acc);
    nq[tid] = acc;
  }
  __syncthreads();

  int tq = (tid >> 4) << 2;     // 4 consecutive t rows
  int aq = (tid & 15) << 2;     // 4 consecutive s (phase 1) / a (phase 2) cols
  float S[4][4];
#pragma unroll
  for (int i = 0; i < 4; ++i)
#pragma unroll
    for (int j = 0; j < 4; ++j) S[i][j] = 0.f;
  for (int b = 0; b < 64; ++b) {
    float qv[4], kv[4];
#pragma unroll
    for (int i = 0; i < 4; ++i) qv[i] = Ql[tq + i][b];
#pragma unroll
    for (int j = 0; j < 4; ++j) kv[j] = KP[aq + j][b];
#pragma unroll
    for (int i = 0; i < 4; ++i)
#pragma unroll
      for (int j = 0; j < 4; ++j) S[i][j] = fmaf(qv[i], kv[j], S[i][j]);
  }
  // gate weights + rowsum
  float ps[4] = {0.f, 0.f, 0.f, 0.f};
#pragma unroll
  for (int i = 0; i < 4; ++i) {
    int t = tq + i;
    float at = cf[t], mtt = ml[t];
#pragma unroll
    for (int j = 0; j < 4; ++j) {
      int s = aq + j;
      float w = (s <= t) ? __expf(at - cf[s] + il[s] - mtt) : 0.f;
      S[i][j] *= w;
      ps[i] += S[i][j];
    }
  }
#pragma unroll
  for (int i = 0; i < 4; ++i) {
    float p = ps[i];
    p += __shfl_xor(p, 1);
    p += __shfl_xor(p, 2);
    p += __shfl_xor(p, 4);
    p += __shfl_xor(p, 8);
    ps[i] = p;
  }
  if ((tid & 15) == 0) {
#pragma unroll
    for (int i = 0; i < 4; ++i) den[tq + i] = ps[i];
  }
  __syncthreads();   // everyone done reading KP as K (and den written)
#pragma unroll
  for (int i = 0; i < 4; ++i)
#pragma unroll
    for (int j = 0; j < 4; ++j) KP[tq + i][aq + j] = S[i][j];
  __syncthreads();   // KP now holds gated P

  float Hh[4][4], inter[4][4];
#pragma unroll
  for (int i = 0; i < 4; ++i)
#pragma unroll
    for (int j = 0; j < 4; ++j) { Hh[i][j] = 0.f; inter[i][j] = 0.f; }
  for (int s = 0; s < 64; ++s) {
    float pv[4], vv[4];
#pragma unroll
    for (int i = 0; i < 4; ++i) pv[i] = KP[tq + i][s];
#pragma unroll
    for (int j = 0; j < 4; ++j) vv[j] = Vl[s][aq + j];
#pragma unroll
    for (int i = 0; i < 4; ++i)
#pragma unroll
      for (int j = 0; j < 4; ++j) Hh[i][j] = fmaf(pv[i], vv[j], Hh[i][j]);
  }
  for (int b = 0; b < 64; ++b) {
    float qv[4], cv[4];
#pragma unroll
    for (int i = 0; i < 4; ++i) qv[i] = Ql[tq + i][b];
#pragma unroll
    for (int j = 0; j < 4; ++j) cv[j] = Cst[aq + j][b];
#pragma unroll
    for (int i = 0; i < 4; ++i)
#pragma unroll
      for (int j = 0; j < 4; ++j) inter[i][j] = fmaf(qv[i], cv[j], inter[i][j]);
  }
#pragma unroll
  for (int i = 0; i < 4; ++i) {
    int t = tq + i;
    float dt = dl[t];
    float dn = fmaf(dt, nq[t], den[t]);
    float rinv = 1.f / fmaxf(fabsf(dn), 1.f);
    const float* orow = P + (size_t)(t0 + t) * NPAD + hb + 192 + aq;
    float4 op4 = *(const float4*)orow;
    float o0 = 1.f / (1.f + __expf(-op4.x));
    float o1 = 1.f / (1.f + __expf(-op4.y));
    float o2 = 1.f / (1.f + __expf(-op4.z));
    float o3 = 1.f / (1.f + __expf(-op4.w));
    float4 st;
    st.x = o0 * (fmaf(dt, inter[i][0], Hh[i][0]) * rinv);
    st.y = o1 * (fmaf(dt, inter[i][1], Hh[i][1]) * rinv);
    st.z = o2 * (fmaf(dt, inter[i][2], Hh[i][2]) * rinv);
    st.w = o3 * (fmaf(dt, inter[i][3], Hh[i][3]) * rinv);
    *(float4*)(out + (size_t)(t0 + t) * 1024 + (h << 6) + aq) = st;
  }
}

// -------------------------------------------------------------------------
extern "C" void kernel_launch(void* const* d_in, const int* in_sizes, int n_in,
                              void* d_out, int out_size, void* d_ws, size_t ws_size,
                              hipStream_t stream) {
  const float* xs   = (const float*)d_in[0];
  const float* ifw  = (const float*)d_in[1];
  const float* ow   = (const float*)d_in[2];
  const float* kqw  = (const float*)d_in[3];
  const float* vw   = (const float*)d_in[4];
  const float* ifb  = (const float*)d_in[5];
  const float* ob   = (const float*)d_in[6];
  const float* kvqb = (const float*)d_in[7];
  float* ws   = (float*)d_ws;
  float* Wp   = ws + OFF_WP;
  float* bias = ws + OFF_BIAS;
  float* Pm   = ws + OFF_P;
  float* Mm   = ws + OFF_M;
  float* DC   = ws + OFF_DC;
  float* DN   = ws + OFF_DN;
  float* DL   = ws + OFF_DL;
  float* outp = (float*)d_out;

  hipLaunchKernelGGL(pack_w, dim3((NPAD * D_IN) / 256), dim3(256), 0, stream,
                     ifw, ow, kqw, vw, ifb, ob, kvqb, Wp, bias);
  hipLaunchKernelGGL(gemm_f32, dim3(NPAD / 128, T_LEN / 128), dim3(256), 0, stream,
                     xs, Wp, bias, Pm);
  hipLaunchKernelGGL(mscan, dim3(NH), dim3(64), 0, stream, Pm, Mm);
  hipLaunchKernelGGL(d1_dc, dim3(NCH * NH), dim3(256), 0, stream, Pm, Mm, DC, DN, DL);
  hipLaunchKernelGGL(d2_prefix, dim3(260), dim3(256), 0, stream, DC, DN, DL);
  hipLaunchKernelGGL(d3_out, dim3(NCH * NH), dim3(256), 0, stream, Pm, Mm, DC, DN, outp);
}

// Round 3
// 617.943 us; speedup vs baseline: 1.9591x; 1.9591x over previous
//
#include <hip/hip_runtime.h>
#include <math.h>

#define T_LEN 8192
#define D_IN  1024
#define NH    16
#define NPAD  4224   // 32 (i/f all heads) + 16*256 (k,q,v,o per head) = 4128, padded
#define NCH   128    // number of 64-step chunks

typedef __attribute__((ext_vector_type(8))) _Float16 f16x8;
typedef __attribute__((ext_vector_type(4))) float f32x4;

// ---- workspace layout (float offsets) ----
static const size_t OFF_WP   = 0;                                  // Wph f16 [NPAD][1024]
static const size_t OFF_BIAS = OFF_WP + (size_t)NPAD * D_IN;       // [NPAD] f32
static const size_t OFF_P    = OFF_BIAS + NPAD;                    // [T][NPAD] f32
static const size_t OFF_M    = OFF_P + (size_t)T_LEN * NPAD;       // [T][16] f32
static const size_t OFF_DC   = OFF_M + (size_t)T_LEN * NH;         // [NCH][16][64][64] f32; ALSO aliases Xh f16 [T][1024] (consumed before DC written)
static const size_t OFF_DN   = OFF_DC + (size_t)NCH * NH * 64 * 64;// [NCH][16][64]
static const size_t OFF_DL   = OFF_DN + (size_t)NCH * NH * 64;     // [NCH][16]

__device__ __forceinline__ void glds16(const void* g, void* l) {
  __builtin_amdgcn_global_load_lds(
      (const __attribute__((address_space(1))) void*)g,
      (__attribute__((address_space(3))) void*)l, 16, 0, 0);
}

// -------------------------------------------------------------------------
// Pack weights into Wph f16 [4224][1024]; row order per head h (base 32+256h):
//   [0..64) k rows (pre-scaled by 1/8), [64..128) q, [128..192) v, [192..256) o
// rows [0..32): i/f interleaved (n=2h+t). bias fp32.
// -------------------------------------------------------------------------
__global__ __launch_bounds__(256) void pack_w(
    const float* __restrict__ ifw, const float* __restrict__ ow,
    const float* __restrict__ kqw, const float* __restrict__ vw,
    const float* __restrict__ ifb, const float* __restrict__ ob,
    const float* __restrict__ kvqb, _Float16* __restrict__ Wph, float* __restrict__ bias) {
  int idx = blockIdx.x * 256 + threadIdx.x;
  int n = idx >> 10, d = idx & 1023;
  float w = 0.f, b = 0.f;
  if (n < 32) {
    int h = n >> 1, t = n & 1;
    w = ifw[(h * 2 + t) * D_IN + d];
    b = ifb[h * 2 + t];
  } else if (n < 4128) {
    int r = n - 32;
    int h = r >> 8, j = r & 255;
    if (j < 64)       { w = kqw[(h * 128 + j) * D_IN + d] * 0.125f; b = kvqb[(h * 3 + 0) * 64 + j]; }
    else if (j < 128) { w = kqw[(h * 128 + j) * D_IN + d];          b = kvqb[(h * 3 + 2) * 64 + (j - 64)]; }
    else if (j < 192) { w = vw[(h * 64 + (j - 128)) * D_IN + d];    b = kvqb[(h * 3 + 1) * 64 + (j - 128)]; }
    else              { w = ow[(h * 64 + (j - 192)) * D_IN + d];    b = ob[h * 64 + (j - 192)]; }
  }
  Wph[(size_t)n * D_IN + d] = (_Float16)w;
  if (d == 0) bias[n] = b;
}

// -------------------------------------------------------------------------
// X fp32 -> f16
// -------------------------------------------------------------------------
__global__ __launch_bounds__(256) void conv_x(const float* __restrict__ X, _Float16* __restrict__ Xh) {
  int i = (blockIdx.x * 256 + threadIdx.x) << 3;
  float4 v0 = *(const float4*)(X + i);
  float4 v1 = *(const float4*)(X + i + 4);
  f16x8 r;
  r[0] = (_Float16)v0.x; r[1] = (_Float16)v0.y; r[2] = (_Float16)v0.z; r[3] = (_Float16)v0.w;
  r[4] = (_Float16)v1.x; r[5] = (_Float16)v1.y; r[6] = (_Float16)v1.z; r[7] = (_Float16)v1.w;
  *(f16x8*)(Xh + i) = r;
}

// -------------------------------------------------------------------------
// f16 MFMA GEMM (m97 structure): P[8192][4224] = Xh * Wph^T + bias (fp32 out)
// 128x128 tile, BK=32, 4 waves (each 64x64 = 4x4 frags of 16x16x32),
// global_load_lds width-16 staging, 2-barrier K-loop.
// -------------------------------------------------------------------------
__global__ __launch_bounds__(256) void gemm_f16(
    const _Float16* __restrict__ Xh, const _Float16* __restrict__ Wph,
    const float* __restrict__ bias, float* __restrict__ P) {
  __shared__ _Float16 As[128 * 32];
  __shared__ _Float16 Bs[128 * 32];
  int tid = threadIdx.x;
  int wave = tid >> 6, lane = tid & 63;
  int m0 = blockIdx.y << 7, n0 = blockIdx.x << 7;
  int wr = wave >> 1, wc = wave & 1;

  f32x4 acc[4][4];
  f32x4 zero = {0.f, 0.f, 0.f, 0.f};
#pragma unroll
  for (int i = 0; i < 4; ++i)
#pragma unroll
    for (int j = 0; j < 4; ++j) acc[i][j] = zero;

  // staging: wave w covers rows [w*32, w*32+32) of the tile in 2 issues of 16 rows
  int srow = lane >> 2;           // 0..15
  int scol = (lane & 3) << 3;     // 0,8,16,24
  const _Float16* ga = Xh + (size_t)(m0 + wave * 32 + srow) * D_IN + scol;
  const _Float16* gb = Wph + (size_t)(n0 + wave * 32 + srow) * D_IN + scol;
  _Float16* la0 = As + (wave * 32) * 32;
  _Float16* la1 = As + (wave * 32 + 16) * 32;
  _Float16* lb0 = Bs + (wave * 32) * 32;
  _Float16* lb1 = Bs + (wave * 32 + 16) * 32;

  int fr = lane & 15;             // fragment row (m or n within 16)
  int fk = (lane >> 4) << 3;      // k offset 0,8,16,24

  for (int k0 = 0; k0 < D_IN; k0 += 32) {
    __syncthreads();              // previous compute done; safe to overwrite LDS
    glds16(ga + k0, la0);
    glds16(ga + 16 * D_IN + k0, la1);
    glds16(gb + k0, lb0);
    glds16(gb + 16 * D_IN + k0, lb1);
    __syncthreads();              // drains vmcnt(0): tile staged

    f16x8 a[4], b[4];
#pragma unroll
    for (int mi = 0; mi < 4; ++mi)
      a[mi] = *(const f16x8*)&As[(wr * 64 + mi * 16 + fr) * 32 + fk];
#pragma unroll
    for (int ni = 0; ni < 4; ++ni)
      b[ni] = *(const f16x8*)&Bs[(wc * 64 + ni * 16 + fr) * 32 + fk];
#pragma unroll
    for (int mi = 0; mi < 4; ++mi)
#pragma unroll
      for (int ni = 0; ni < 4; ++ni)
        acc[mi][ni] = __builtin_amdgcn_mfma_f32_16x16x32_f16(a[mi], b[ni], acc[mi][ni], 0, 0, 0);
  }

  // epilogue: C/D layout col=lane&15, row=(lane>>4)*4+reg (dtype-independent, m89/m121)
  int cr = (lane >> 4) << 2;
  int cc = lane & 15;
#pragma unroll
  for (int mi = 0; mi < 4; ++mi) {
#pragma unroll
    for (int ni = 0; ni < 4; ++ni) {
      int col = n0 + wc * 64 + ni * 16 + cc;
      float bb = bias[col];
      size_t base = (size_t)(m0 + wr * 64 + mi * 16 + cr) * NPAD + col;
#pragma unroll
      for (int r = 0; r < 4; ++r)
        P[base + (size_t)r * NPAD] = acc[mi][ni][r] + bb;
    }
  }
}

// -------------------------------------------------------------------------
// fp32 exact i/f columns: overwrite P[:, 0:32] (gate precision guard)
// -------------------------------------------------------------------------
__global__ __launch_bounds__(256) void gemm_if(
    const float* __restrict__ X, const float* __restrict__ ifw,
    const float* __restrict__ ifb, float* __restrict__ P) {
  int row = blockIdx.x * 8 + (threadIdx.x >> 5);
  int n = threadIdx.x & 31;
  const float* xr = X + (size_t)row * D_IN;
  const float* wr = ifw + (size_t)n * D_IN;
  float acc = 0.f;
#pragma unroll 8
  for (int k = 0; k < D_IN; k += 4) {
    float4 xv = *(const float4*)(xr + k);
    float4 wv = *(const float4*)(wr + k);
    acc = fmaf(xv.x, wv.x, acc);
    acc = fmaf(xv.y, wv.y, acc);
    acc = fmaf(xv.z, wv.z, acc);
    acc = fmaf(xv.w, wv.w, acc);
  }
  P[(size_t)row * NPAD + n] = acc + ifb[n];
}

// -------------------------------------------------------------------------
// m-scan: m_t = max(f_t + m_{t-1}, i_t), m_{-1}=0.
// -------------------------------------------------------------------------
__global__ __launch_bounds__(64) void mscan(const float* __restrict__ P, float* __restrict__ M) {
  int h = blockIdx.x, lane = threadIdx.x;
  __shared__ float sI[64], sF[64];
  float m = 0.f;
  float2 v0 = *(const float2*)(P + (size_t)lane * NPAD + 2 * h);
  float ri = v0.x, rf = v0.y;
  for (int c = 0; c < NCH; ++c) {
    __syncthreads();
    sI[lane] = ri; sF[lane] = rf;
    __syncthreads();
    if (c < NCH - 1) {
      int t = (c + 1) * 64 + lane;
      float2 v = *(const float2*)(P + (size_t)t * NPAD + 2 * h);
      ri = v.x; rf = v.y;
    }
    float myM = 0.f;
#pragma unroll 8
    for (int u = 0; u < 64; ++u) {
      m = fmaxf(sF[u] + m, sI[u]);
      myM = (u == lane) ? m : myM;
    }
    M[(size_t)(c * 64 + lane) * NH + h] = myM;
  }
}

// -------------------------------------------------------------------------
// D1: per (chunk,head): DC = sum_s g_s v_s k_s^T,  DN = sum_s g_s k_s,
//     DL = chunk decay,  with g_s = exp(cumF_L - cumF_s + i_s - m_L).
// -------------------------------------------------------------------------
__global__ __launch_bounds__(256) void d1_dc(
    const float* __restrict__ P, const float* __restrict__ M,
    float* __restrict__ DC, float* __restrict__ DN, float* __restrict__ DL) {
  int c = blockIdx.x >> 4, h = blockIdx.x & 15;
  int t0 = c << 6, hb = 32 + (h << 8);
  int tid = threadIdx.x;
  __shared__ float Kl[64][65];
  __shared__ float Vl[64][65];
  __shared__ float gl[64];
#pragma unroll
  for (int i = 0; i < 4; ++i) {
    int fq = (i << 8) + tid;
    int s = fq >> 4, b4 = (fq & 15) << 2;
    const float* row = P + (size_t)(t0 + s) * NPAD + hb;
    float4 kv = *(const float4*)(row + b4);
    float4 vv = *(const float4*)(row + 128 + b4);
    Kl[s][b4 + 0] = kv.x; Kl[s][b4 + 1] = kv.y; Kl[s][b4 + 2] = kv.z; Kl[s][b4 + 3] = kv.w;
    Vl[s][b4 + 0] = vv.x; Vl[s][b4 + 1] = vv.y; Vl[s][b4 + 2] = vv.z; Vl[s][b4 + 3] = vv.w;
  }
  if (tid < 64) {
    float2 iff = *(const float2*)(P + (size_t)(t0 + tid) * NPAD + (h << 1));
    float iv = iff.x, fv = iff.y;
    float cs = fv;
#pragma unroll
    for (int dd = 1; dd < 64; dd <<= 1) {
      float o = __shfl_up(cs, dd, 64);
      cs += (tid >= dd) ? o : 0.f;
    }
    float cumL = __shfl(cs, 63, 64);
    float mL = M[(size_t)(t0 + 63) * NH + h];
    gl[tid] = __expf(cumL - cs + iv - mL);
    if (tid == 0) {
      float mstart = (c > 0) ? M[(size_t)(t0 - 1) * NH + h] : 0.f;
      DL[(c << 4) + h] = __expf(mstart + cumL - mL);
    }
  }
  __syncthreads();
  if (tid < 64) {
    float acc = 0.f;
#pragma unroll
    for (int s = 0; s < 64; ++s) acc = fmaf(gl[s], Kl[s][tid], acc);
    DN[((size_t)(c << 4) + h) * 64 + tid] = acc;
  }
  int a = tid & 63, bq = tid >> 6;
  float acc[16];
#pragma unroll
  for (int j = 0; j < 16; ++j) acc[j] = 0.f;
  for (int s = 0; s < 64; ++s) {
    float gv = gl[s] * Vl[s][a];
#pragma unroll
    for (int j = 0; j < 16; ++j) acc[j] = fmaf(gv, Kl[s][(bq << 4) + j], acc[j]);
  }
  size_t base = (((size_t)(c << 4) + h) << 12) + ((size_t)a << 6) + (bq << 4);
#pragma unroll
  for (int j4 = 0; j4 < 16; j4 += 4) {
    float4 st; st.x = acc[j4]; st.y = acc[j4 + 1]; st.z = acc[j4 + 2]; st.w = acc[j4 + 3];
    *(float4*)(DC + base + j4) = st;
  }
}

// -------------------------------------------------------------------------
// D2: in-place weighted prefix over chunks.
// -------------------------------------------------------------------------
__global__ __launch_bounds__(256) void d2_prefix(
    float* __restrict__ DC, float* __restrict__ DN, const float* __restrict__ DL) {
  int bid = blockIdx.x, tid = threadIdx.x;
  if (bid < 256) {
    int e = (bid << 8) + tid;
    int h = e >> 12, pos = e & 4095;
    float carry = 0.f;
    size_t idx = ((size_t)h << 12) + pos;
    float v = DC[idx];
    for (int c = 0; c < NCH; ++c) {
      float dl = DL[(c << 4) + h];
      float vn = (c < NCH - 1) ? DC[idx + 65536] : 0.f;
      DC[idx] = carry;
      carry = fmaf(dl, carry, v);
      v = vn;
      idx += 65536;
    }
  } else {
    int e = ((bid - 256) << 8) + tid;
    int h = e >> 6, b = e & 63;
    float carry = 0.f;
    size_t idx = ((size_t)h << 6) + b;
    float v = DN[idx];
    for (int c = 0; c < NCH; ++c) {
      float dl = DL[(c << 4) + h];
      float vn = (c < NCH - 1) ? DN[idx + 1024] : 0.f;
      DN[idx] = carry;
      carry = fmaf(dl, carry, v);
      v = vn;
      idx += 1024;
    }
  }
}

// -------------------------------------------------------------------------
// D3: per (chunk,head) outputs.
// -------------------------------------------------------------------------
__global__ __launch_bounds__(256) void d3_out(
    const float* __restrict__ P, const float* __restrict__ M,
    const float* __restrict__ CS, const float* __restrict__ NS,
    float* __restrict__ out) {
  int c = blockIdx.x >> 4, h = blockIdx.x & 15;
  int t0 = c << 6, hb = 32 + (h << 8);
  int tid = threadIdx.x;
  __shared__ float KP[64][65];   // K, later overwritten with P=W.*S
  __shared__ float Ql[64][65];
  __shared__ float Vl[64][65];
  __shared__ float Cst[64][65];
  __shared__ float cf[64], il[64], ml[64], dl[64], nq[64], den[64], nsl[64];
#pragma unroll
  for (int i = 0; i < 4; ++i) {
    int fq = (i << 8) + tid;
    int s = fq >> 4, b4 = (fq & 15) << 2;
    const float* row = P + (size_t)(t0 + s) * NPAD + hb;
    float4 kv = *(const float4*)(row + b4);
    float4 qv = *(const float4*)(row + 64 + b4);
    float4 vv = *(const float4*)(row + 128 + b4);
    float4 cv = *(const float4*)(CS + ((((size_t)(c << 4)) + h) << 12) + ((size_t)s << 6) + b4);
    KP[s][b4 + 0] = kv.x; KP[s][b4 + 1] = kv.y; KP[s][b4 + 2] = kv.z; KP[s][b4 + 3] = kv.w;
    Ql[s][b4 + 0] = qv.x; Ql[s][b4 + 1] = qv.y; Ql[s][b4 + 2] = qv.z; Ql[s][b4 + 3] = qv.w;
    Vl[s][b4 + 0] = vv.x; Vl[s][b4 + 1] = vv.y; Vl[s][b4 + 2] = vv.z; Vl[s][b4 + 3] = vv.w;
    Cst[s][b4 + 0] = cv.x; Cst[s][b4 + 1] = cv.y; Cst[s][b4 + 2] = cv.z; Cst[s][b4 + 3] = cv.w;
  }
  float iv = 0.f, mt = 0.f, cs = 0.f;
  if (tid < 64) {
    float2 iff = *(const float2*)(P + (size_t)(t0 + tid) * NPAD + (h << 1));
    iv = iff.x;
    float fv = iff.y;
    mt = M[(size_t)(t0 + tid) * NH + h];
    nsl[tid] = NS[((size_t)(c << 4) + h) * 64 + tid];
    cs = fv;
#pragma unroll
    for (int dd = 1; dd < 64; dd <<= 1) {
      float o = __shfl_up(cs, dd, 64);
      cs += (tid >= dd) ? o : 0.f;
    }
  }
  __syncthreads();
  if (tid < 64) {
    cf[tid] = cs; il[tid] = iv; ml[tid] = mt;
    float mstart = (c > 0) ? M[(size_t)(t0 - 1) * NH + h] : 0.f;
    dl[tid] = __expf(mstart + cs - mt);
    float acc = 0.f;
#pragma unroll
    for (int b = 0; b < 64; ++b) acc = fmaf(nsl[b], Ql[tid][b], acc);
    nq[tid] = acc;
  }
  __syncthreads();

  int tq = (tid >> 4) << 2;
  int aq = (tid & 15) << 2;
  float S[4][4];
#pragma unroll
  for (int i = 0; i < 4; ++i)
#pragma unroll
    for (int j = 0; j < 4; ++j) S[i][j] = 0.f;
  for (int b = 0; b < 64; ++b) {
    float qv[4], kv[4];
#pragma unroll
    for (int i = 0; i < 4; ++i) qv[i] = Ql[tq + i][b];
#pragma unroll
    for (int j = 0; j < 4; ++j) kv[j] = KP[aq + j][b];
#pragma unroll
    for (int i = 0; i < 4; ++i)
#pragma unroll
      for (int j = 0; j < 4; ++j) S[i][j] = fmaf(qv[i], kv[j], S[i][j]);
  }
  float ps[4] = {0.f, 0.f, 0.f, 0.f};
#pragma unroll
  for (int i = 0; i < 4; ++i) {
    int t = tq + i;
    float at = cf[t], mtt = ml[t];
#pragma unroll
    for (int j = 0; j < 4; ++j) {
      int s = aq + j;
      float w = (s <= t) ? __expf(at - cf[s] + il[s] - mtt) : 0.f;
      S[i][j] *= w;
      ps[i] += S[i][j];
    }
  }
#pragma unroll
  for (int i = 0; i < 4; ++i) {
    float p = ps[i];
    p += __shfl_xor(p, 1);
    p += __shfl_xor(p, 2);
    p += __shfl_xor(p, 4);
    p += __shfl_xor(p, 8);
    ps[i] = p;
  }
  if ((tid & 15) == 0) {
#pragma unroll
    for (int i = 0; i < 4; ++i) den[tq + i] = ps[i];
  }
  __syncthreads();
#pragma unroll
  for (int i = 0; i < 4; ++i)
#pragma unroll
    for (int j = 0; j < 4; ++j) KP[tq + i][aq + j] = S[i][j];
  __syncthreads();

  float Hh[4][4], inter[4][4];
#pragma unroll
  for (int i = 0; i < 4; ++i)
#pragma unroll
    for (int j = 0; j < 4; ++j) { Hh[i][j] = 0.f; inter[i][j] = 0.f; }
  for (int s = 0; s < 64; ++s) {
    float pv[4], vv[4];
#pragma unroll
    for (int i = 0; i < 4; ++i) pv[i] = KP[tq + i][s];
#pragma unroll
    for (int j = 0; j < 4; ++j) vv[j] = Vl[s][aq + j];
#pragma unroll
    for (int i = 0; i < 4; ++i)
#pragma unroll
      for (int j = 0; j < 4; ++j) Hh[i][j] = fmaf(pv[i], vv[j], Hh[i][j]);
  }
  for (int b = 0; b < 64; ++b) {
    float qv[4], cv[4];
#pragma unroll
    for (int i = 0; i < 4; ++i) qv[i] = Ql[tq + i][b];
#pragma unroll
    for (int j = 0; j < 4; ++j) cv[j] = Cst[aq + j][b];
#pragma unroll
    for (int i = 0; i < 4; ++i)
#pragma unroll
      for (int j = 0; j < 4; ++j) inter[i][j] = fmaf(qv[i], cv[j], inter[i][j]);
  }
#pragma unroll
  for (int i = 0; i < 4; ++i) {
    int t = tq + i;
    float dt = dl[t];
    float dn = fmaf(dt, nq[t], den[t]);
    float rinv = 1.f / fmaxf(fabsf(dn), 1.f);
    const float* orow = P + (size_t)(t0 + t) * NPAD + hb + 192 + aq;
    float4 op4 = *(const float4*)orow;
    float o0 = 1.f / (1.f + __expf(-op4.x));
    float o1 = 1.f / (1.f + __expf(-op4.y));
    float o2 = 1.f / (1.f + __expf(-op4.z));
    float o3 = 1.f / (1.f + __expf(-op4.w));
    float4 st;
    st.x = o0 * (fmaf(dt, inter[i][0], Hh[i][0]) * rinv);
    st.y = o1 * (fmaf(dt, inter[i][1], Hh[i][1]) * rinv);
    st.z = o2 * (fmaf(dt, inter[i][2], Hh[i][2]) * rinv);
    st.w = o3 * (fmaf(dt, inter[i][3], Hh[i][3]) * rinv);
    *(float4*)(out + (size_t)(t0 + t) * 1024 + (h << 6) + aq) = st;
  }
}

// -------------------------------------------------------------------------
extern "C" void kernel_launch(void* const* d_in, const int* in_sizes, int n_in,
                              void* d_out, int out_size, void* d_ws, size_t ws_size,
                              hipStream_t stream) {
  const float* xs   = (const float*)d_in[0];
  const float* ifw  = (const float*)d_in[1];
  const float* ow   = (const float*)d_in[2];
  const float* kqw  = (const float*)d_in[3];
  const float* vw   = (const float*)d_in[4];
  const float* ifb  = (const float*)d_in[5];
  const float* ob   = (const float*)d_in[6];
  const float* kvqb = (const float*)d_in[7];
  float* ws   = (float*)d_ws;
  _Float16* Wph = (_Float16*)(ws + OFF_WP);
  float* bias = ws + OFF_BIAS;
  float* Pm   = ws + OFF_P;
  float* Mm   = ws + OFF_M;
  float* DC   = ws + OFF_DC;
  _Float16* Xh = (_Float16*)(ws + OFF_DC);   // alias: consumed by gemm before d1 writes DC
  float* DN   = ws + OFF_DN;
  float* DL   = ws + OFF_DL;
  float* outp = (float*)d_out;

  hipLaunchKernelGGL(pack_w, dim3((NPAD * D_IN) / 256), dim3(256), 0, stream,
                     ifw, ow, kqw, vw, ifb, ob, kvqb, Wph, bias);
  hipLaunchKernelGGL(conv_x, dim3((T_LEN * D_IN / 8) / 256), dim3(256), 0, stream, xs, Xh);
  hipLaunchKernelGGL(gemm_f16, dim3(NPAD / 128, T_LEN / 128), dim3(256), 0, stream,
                     Xh, Wph, bias, Pm);
  hipLaunchKernelGGL(gemm_if, dim3(T_LEN / 8), dim3(256), 0, stream, xs, ifw, ifb, Pm);
  hipLaunchKernelGGL(mscan, dim3(NH), dim3(64), 0, stream, Pm, Mm);
  hipLaunchKernelGGL(d1_dc, dim3(NCH * NH), dim3(256), 0, stream, Pm, Mm, DC, DN, DL);
  hipLaunchKernelGGL(d2_prefix, dim3(260), dim3(256), 0, stream, DC, DN, DL);
  hipLaunchKernelGGL(d3_out, dim3(NCH * NH), dim3(256), 0, stream, Pm, Mm, DC, DN, outp);
}

// Round 4
// 431.333 us; speedup vs baseline: 2.8067x; 1.4326x over previous
//
#include <hip/hip_runtime.h>
#include <math.h>

#define T_LEN 8192
#define D_IN  1024
#define NH    16
#define NPAD  4224   // 32 (i/f all heads) + 16*256 (k,q,v,o per head) = 4128, padded
#define NCH   128    // number of 64-step chunks

typedef __attribute__((ext_vector_type(8))) _Float16 f16x8;
typedef __attribute__((ext_vector_type(4))) float f32x4;

// ---- workspace layout (float offsets) ----
static const size_t OFF_WP   = 0;                                  // Wph f16 [NPAD][1024]
static const size_t OFF_BIAS = OFF_WP + (size_t)NPAD * D_IN;       // [NPAD] f32
static const size_t OFF_P    = OFF_BIAS + NPAD;                    // [T][NPAD] f32
static const size_t OFF_M    = OFF_P + (size_t)T_LEN * NPAD;       // [T][16] f32
static const size_t OFF_DC   = OFF_M + (size_t)T_LEN * NH;         // [NCH][16][64][64] f32; ALSO aliases Xh f16 [T][1024] (consumed before DC written)
static const size_t OFF_DN   = OFF_DC + (size_t)NCH * NH * 64 * 64;// [NCH][16][64]
static const size_t OFF_DL   = OFF_DN + (size_t)NCH * NH * 64;     // [NCH][16]
static const size_t OFF_IF   = OFF_DL + (size_t)NCH * NH;          // IFc [T][32] compact i/f

__device__ __forceinline__ void glds16(const void* g, void* l) {
  __builtin_amdgcn_global_load_lds(
      (const __attribute__((address_space(1))) void*)g,
      (__attribute__((address_space(3))) void*)l, 16, 0, 0);
}

// -------------------------------------------------------------------------
// Pack weights into Wph f16 [4224][1024]; row order per head h (base 32+256h):
//   [0..64) k rows (pre-scaled by 1/8), [64..128) q, [128..192) v, [192..256) o
// rows [0..32): i/f interleaved (n=2h+t). bias fp32.
// -------------------------------------------------------------------------
__global__ __launch_bounds__(256) void pack_w(
    const float* __restrict__ ifw, const float* __restrict__ ow,
    const float* __restrict__ kqw, const float* __restrict__ vw,
    const float* __restrict__ ifb, const float* __restrict__ ob,
    const float* __restrict__ kvqb, _Float16* __restrict__ Wph, float* __restrict__ bias) {
  int idx = blockIdx.x * 256 + threadIdx.x;
  int n = idx >> 10, d = idx & 1023;
  float w = 0.f, b = 0.f;
  if (n < 32) {
    int h = n >> 1, t = n & 1;
    w = ifw[(h * 2 + t) * D_IN + d];
    b = ifb[h * 2 + t];
  } else if (n < 4128) {
    int r = n - 32;
    int h = r >> 8, j = r & 255;
    if (j < 64)       { w = kqw[(h * 128 + j) * D_IN + d] * 0.125f; b = kvqb[(h * 3 + 0) * 64 + j]; }
    else if (j < 128) { w = kqw[(h * 128 + j) * D_IN + d];          b = kvqb[(h * 3 + 2) * 64 + (j - 64)]; }
    else if (j < 192) { w = vw[(h * 64 + (j - 128)) * D_IN + d];    b = kvqb[(h * 3 + 1) * 64 + (j - 128)]; }
    else              { w = ow[(h * 64 + (j - 192)) * D_IN + d];    b = ob[h * 64 + (j - 192)]; }
  }
  Wph[(size_t)n * D_IN + d] = (_Float16)w;
  if (d == 0) bias[n] = b;
}

// -------------------------------------------------------------------------
// X fp32 -> f16
// -------------------------------------------------------------------------
__global__ __launch_bounds__(256) void conv_x(const float* __restrict__ X, _Float16* __restrict__ Xh) {
  int i = (blockIdx.x * 256 + threadIdx.x) << 3;
  float4 v0 = *(const float4*)(X + i);
  float4 v1 = *(const float4*)(X + i + 4);
  f16x8 r;
  r[0] = (_Float16)v0.x; r[1] = (_Float16)v0.y; r[2] = (_Float16)v0.z; r[3] = (_Float16)v0.w;
  r[4] = (_Float16)v1.x; r[5] = (_Float16)v1.y; r[6] = (_Float16)v1.z; r[7] = (_Float16)v1.w;
  *(f16x8*)(Xh + i) = r;
}

// -------------------------------------------------------------------------
// f16 MFMA GEMM (m97 structure): P[8192][4224] = Xh * Wph^T + bias (fp32 out)
// -------------------------------------------------------------------------
__global__ __launch_bounds__(256) void gemm_f16(
    const _Float16* __restrict__ Xh, const _Float16* __restrict__ Wph,
    const float* __restrict__ bias, float* __restrict__ P) {
  __shared__ _Float16 As[128 * 32];
  __shared__ _Float16 Bs[128 * 32];
  int tid = threadIdx.x;
  int wave = tid >> 6, lane = tid & 63;
  int m0 = blockIdx.y << 7, n0 = blockIdx.x << 7;
  int wr = wave >> 1, wc = wave & 1;

  f32x4 acc[4][4];
  f32x4 zero = {0.f, 0.f, 0.f, 0.f};
#pragma unroll
  for (int i = 0; i < 4; ++i)
#pragma unroll
    for (int j = 0; j < 4; ++j) acc[i][j] = zero;

  int srow = lane >> 2;           // 0..15
  int scol = (lane & 3) << 3;     // 0,8,16,24
  const _Float16* ga = Xh + (size_t)(m0 + wave * 32 + srow) * D_IN + scol;
  const _Float16* gb = Wph + (size_t)(n0 + wave * 32 + srow) * D_IN + scol;
  _Float16* la0 = As + (wave * 32) * 32;
  _Float16* la1 = As + (wave * 32 + 16) * 32;
  _Float16* lb0 = Bs + (wave * 32) * 32;
  _Float16* lb1 = Bs + (wave * 32 + 16) * 32;

  int fr = lane & 15;             // fragment row
  int fk = (lane >> 4) << 3;      // k offset 0,8,16,24

  for (int k0 = 0; k0 < D_IN; k0 += 32) {
    __syncthreads();
    glds16(ga + k0, la0);
    glds16(ga + 16 * D_IN + k0, la1);
    glds16(gb + k0, lb0);
    glds16(gb + 16 * D_IN + k0, lb1);
    __syncthreads();

    f16x8 a[4], b[4];
#pragma unroll
    for (int mi = 0; mi < 4; ++mi)
      a[mi] = *(const f16x8*)&As[(wr * 64 + mi * 16 + fr) * 32 + fk];
#pragma unroll
    for (int ni = 0; ni < 4; ++ni)
      b[ni] = *(const f16x8*)&Bs[(wc * 64 + ni * 16 + fr) * 32 + fk];
#pragma unroll
    for (int mi = 0; mi < 4; ++mi)
#pragma unroll
      for (int ni = 0; ni < 4; ++ni)
        acc[mi][ni] = __builtin_amdgcn_mfma_f32_16x16x32_f16(a[mi], b[ni], acc[mi][ni], 0, 0, 0);
  }

  int cr = (lane >> 4) << 2;
  int cc = lane & 15;
#pragma unroll
  for (int mi = 0; mi < 4; ++mi) {
#pragma unroll
    for (int ni = 0; ni < 4; ++ni) {
      int col = n0 + wc * 64 + ni * 16 + cc;
      float bb = bias[col];
      size_t base = (size_t)(m0 + wr * 64 + mi * 16 + cr) * NPAD + col;
#pragma unroll
      for (int r = 0; r < 4; ++r)
        P[base + (size_t)r * NPAD] = acc[mi][ni][r] + bb;
    }
  }
}

// -------------------------------------------------------------------------
// fp32 exact i/f columns: overwrite P[:, 0:32] AND write compact IFc[T][32]
// -------------------------------------------------------------------------
__global__ __launch_bounds__(256) void gemm_if(
    const float* __restrict__ X, const float* __restrict__ ifw,
    const float* __restrict__ ifb, float* __restrict__ P, float* __restrict__ IFc) {
  int row = blockIdx.x * 8 + (threadIdx.x >> 5);
  int n = threadIdx.x & 31;
  const float* xr = X + (size_t)row * D_IN;
  const float* wr = ifw + (size_t)n * D_IN;
  float acc = 0.f;
#pragma unroll 8
  for (int k = 0; k < D_IN; k += 4) {
    float4 xv = *(const float4*)(xr + k);
    float4 wv = *(const float4*)(wr + k);
    acc = fmaf(xv.x, wv.x, acc);
    acc = fmaf(xv.y, wv.y, acc);
    acc = fmaf(xv.z, wv.z, acc);
    acc = fmaf(xv.w, wv.w, acc);
  }
  float v = acc + ifb[n];
  P[(size_t)row * NPAD + n] = v;
  IFc[(size_t)row * 32 + n] = v;
}

// -------------------------------------------------------------------------
// Parallel m-scan: m_t = max(f_t + m_{t-1}, i_t), m_{-1}=0.
// g_{f,i}(m)=max(m+f,i) composes as (F1,I1)o(F2,I2)=(F1+F2, max(I1+F2,I2)).
// 16 blocks (1 head) x 256 threads; 32-step segments; shfl+LDS scan.
// -------------------------------------------------------------------------
__global__ __launch_bounds__(256) void mscan(const float* __restrict__ IFc, float* __restrict__ M) {
  int h = blockIdx.x;
  int tid = threadIdx.x;
  int lane = tid & 63, wv = tid >> 6;
  int t0 = tid << 5;
  // phase 1: compose own 32-step segment
  float F = 0.f, I = -1e30f;
#pragma unroll 8
  for (int u = 0; u < 32; ++u) {
    float2 v = *(const float2*)(IFc + ((size_t)(t0 + u) << 5) + (h << 1));
    I = fmaxf(I + v.y, v.x);
    F += v.y;
  }
  // phase 2a: wave-level inclusive scan (non-commutative compose)
#pragma unroll
  for (int d = 1; d < 64; d <<= 1) {
    float Fo = __shfl_up(F, d, 64);
    float Io = __shfl_up(I, d, 64);
    if (lane >= d) { I = fmaxf(Io + F, I); F = Fo + F; }
  }
  __shared__ float sF[4], sI[4];
  if (lane == 63) { sF[wv] = F; sI[wv] = I; }
  // exclusive within wave
  float Fe = __shfl_up(F, 1, 64);
  float Ie = __shfl_up(I, 1, 64);
  if (lane == 0) { Fe = 0.f; Ie = -1e30f; }
  __syncthreads();
  // phase 2b: compose aggregates of previous waves
  float Fp = 0.f, Ip = -1e30f;
  for (int w = 0; w < wv; ++w) { Ip = fmaxf(Ip + sF[w], sI[w]); Fp += sF[w]; }
  float Ft = Fp + Fe;
  float It = fmaxf(Ip + Fe, Ie);
  float m = fmaxf(Ft, It);   // prefix applied to m_{-1}=0
  // phase 3: replay segment with incoming prefix
#pragma unroll 8
  for (int u = 0; u < 32; ++u) {
    float2 v = *(const float2*)(IFc + ((size_t)(t0 + u) << 5) + (h << 1));
    m = fmaxf(v.y + m, v.x);
    M[(size_t)(t0 + u) * NH + h] = m;
  }
}

// -------------------------------------------------------------------------
// D1: per (chunk,head): DC = sum_s g_s v_s k_s^T,  DN = sum_s g_s k_s,
//     DL = chunk decay,  with g_s = exp(cumF_L - cumF_s + i_s - m_L).
// -------------------------------------------------------------------------
__global__ __launch_bounds__(256) void d1_dc(
    const float* __restrict__ P, const float* __restrict__ M,
    float* __restrict__ DC, float* __restrict__ DN, float* __restrict__ DL) {
  int c = blockIdx.x >> 4, h = blockIdx.x & 15;
  int t0 = c << 6, hb = 32 + (h << 8);
  int tid = threadIdx.x;
  __shared__ float Kl[64][65];
  __shared__ float Vl[64][65];
  __shared__ float gl[64];
#pragma unroll
  for (int i = 0; i < 4; ++i) {
    int fq = (i << 8) + tid;
    int s = fq >> 4, b4 = (fq & 15) << 2;
    const float* row = P + (size_t)(t0 + s) * NPAD + hb;
    float4 kv = *(const float4*)(row + b4);
    float4 vv = *(const float4*)(row + 128 + b4);
    Kl[s][b4 + 0] = kv.x; Kl[s][b4 + 1] = kv.y; Kl[s][b4 + 2] = kv.z; Kl[s][b4 + 3] = kv.w;
    Vl[s][b4 + 0] = vv.x; Vl[s][b4 + 1] = vv.y; Vl[s][b4 + 2] = vv.z; Vl[s][b4 + 3] = vv.w;
  }
  if (tid < 64) {
    float2 iff = *(const float2*)(P + (size_t)(t0 + tid) * NPAD + (h << 1));
    float iv = iff.x, fv = iff.y;
    float cs = fv;
#pragma unroll
    for (int dd = 1; dd < 64; dd <<= 1) {
      float o = __shfl_up(cs, dd, 64);
      cs += (tid >= dd) ? o : 0.f;
    }
    float cumL = __shfl(cs, 63, 64);
    float mL = M[(size_t)(t0 + 63) * NH + h];
    gl[tid] = __expf(cumL - cs + iv - mL);
    if (tid == 0) {
      float mstart = (c > 0) ? M[(size_t)(t0 - 1) * NH + h] : 0.f;
      DL[(c << 4) + h] = __expf(mstart + cumL - mL);
    }
  }
  __syncthreads();
  if (tid < 64) {
    float acc = 0.f;
#pragma unroll
    for (int s = 0; s < 64; ++s) acc = fmaf(gl[s], Kl[s][tid], acc);
    DN[((size_t)(c << 4) + h) * 64 + tid] = acc;
  }
  int a = tid & 63, bq = tid >> 6;
  float acc[16];
#pragma unroll
  for (int j = 0; j < 16; ++j) acc[j] = 0.f;
  for (int s = 0; s < 64; ++s) {
    float gv = gl[s] * Vl[s][a];
#pragma unroll
    for (int j = 0; j < 16; ++j) acc[j] = fmaf(gv, Kl[s][(bq << 4) + j], acc[j]);
  }
  size_t base = (((size_t)(c << 4) + h) << 12) + ((size_t)a << 6) + (bq << 4);
#pragma unroll
  for (int j4 = 0; j4 < 16; j4 += 4) {
    float4 st; st.x = acc[j4]; st.y = acc[j4 + 1]; st.z = acc[j4 + 2]; st.w = acc[j4 + 3];
    *(float4*)(DC + base + j4) = st;
  }
}

// -------------------------------------------------------------------------
// D2: in-place weighted prefix over chunks.
// -------------------------------------------------------------------------
__global__ __launch_bounds__(256) void d2_prefix(
    float* __restrict__ DC, float* __restrict__ DN, const float* __restrict__ DL) {
  int bid = blockIdx.x, tid = threadIdx.x;
  if (bid < 256) {
    int e = (bid << 8) + tid;
    int h = e >> 12, pos = e & 4095;
    float carry = 0.f;
    size_t idx = ((size_t)h << 12) + pos;
    float v = DC[idx];
    for (int c = 0; c < NCH; ++c) {
      float dl = DL[(c << 4) + h];
      float vn = (c < NCH - 1) ? DC[idx + 65536] : 0.f;
      DC[idx] = carry;
      carry = fmaf(dl, carry, v);
      v = vn;
      idx += 65536;
    }
  } else {
    int e = ((bid - 256) << 8) + tid;
    int h = e >> 6, b = e & 63;
    float carry = 0.f;
    size_t idx = ((size_t)h << 6) + b;
    float v = DN[idx];
    for (int c = 0; c < NCH; ++c) {
      float dl = DL[(c << 4) + h];
      float vn = (c < NCH - 1) ? DN[idx + 1024] : 0.f;
      DN[idx] = carry;
      carry = fmaf(dl, carry, v);
      v = vn;
      idx += 1024;
    }
  }
}

// -------------------------------------------------------------------------
// D3: per (chunk,head) outputs.
// -------------------------------------------------------------------------
__global__ __launch_bounds__(256) void d3_out(
    const float* __restrict__ P, const float* __restrict__ M,
    const float* __restrict__ CS, const float* __restrict__ NS,
    float* __restrict__ out) {
  int c = blockIdx.x >> 4, h = blockIdx.x & 15;
  int t0 = c << 6, hb = 32 + (h << 8);
  int tid = threadIdx.x;
  __shared__ float KP[64][65];   // K, later overwritten with P=W.*S
  __shared__ float Ql[64][65];
  __shared__ float Vl[64][65];
  __shared__ float Cst[64][65];
  __shared__ float cf[64], il[64], ml[64], dl[64], nq[64], den[64], nsl[64];
#pragma unroll
  for (int i = 0; i < 4; ++i) {
    int fq = (i << 8) + tid;
    int s = fq >> 4, b4 = (fq & 15) << 2;
    const float* row = P + (size_t)(t0 + s) * NPAD + hb;
    float4 kv = *(const float4*)(row + b4);
    float4 qv = *(const float4*)(row + 64 + b4);
    float4 vv = *(const float4*)(row + 128 + b4);
    float4 cv = *(const float4*)(CS + ((((size_t)(c << 4)) + h) << 12) + ((size_t)s << 6) + b4);
    KP[s][b4 + 0] = kv.x; KP[s][b4 + 1] = kv.y; KP[s][b4 + 2] = kv.z; KP[s][b4 + 3] = kv.w;
    Ql[s][b4 + 0] = qv.x; Ql[s][b4 + 1] = qv.y; Ql[s][b4 + 2] = qv.z; Ql[s][b4 + 3] = qv.w;
    Vl[s][b4 + 0] = vv.x; Vl[s][b4 + 1] = vv.y; Vl[s][b4 + 2] = vv.z; Vl[s][b4 + 3] = vv.w;
    Cst[s][b4 + 0] = cv.x; Cst[s][b4 + 1] = cv.y; Cst[s][b4 + 2] = cv.z; Cst[s][b4 + 3] = cv.w;
  }
  float iv = 0.f, mt = 0.f, cs = 0.f;
  if (tid < 64) {
    float2 iff = *(const float2*)(P + (size_t)(t0 + tid) * NPAD + (h << 1));
    iv = iff.x;
    float fv = iff.y;
    mt = M[(size_t)(t0 + tid) * NH + h];
    nsl[tid] = NS[((size_t)(c << 4) + h) * 64 + tid];
    cs = fv;
#pragma unroll
    for (int dd = 1; dd < 64; dd <<= 1) {
      float o = __shfl_up(cs, dd, 64);
      cs += (tid >= dd) ? o : 0.f;
    }
  }
  __syncthreads();
  if (tid < 64) {
    cf[tid] = cs; il[tid] = iv; ml[tid] = mt;
    float mstart = (c > 0) ? M[(size_t)(t0 - 1) * NH + h] : 0.f;
    dl[tid] = __expf(mstart + cs - mt);
    float acc = 0.f;
#pragma unroll
    for (int b = 0; b < 64; ++b) acc = fmaf(nsl[b], Ql[tid][b], acc);
    nq[tid] = acc;
  }
  __syncthreads();

  int tq = (tid >> 4) << 2;
  int aq = (tid & 15) << 2;
  float S[4][4];
#pragma unroll
  for (int i = 0; i < 4; ++i)
#pragma unroll
    for (int j = 0; j < 4; ++j) S[i][j] = 0.f;
  for (int b = 0; b < 64; ++b) {
    float qv[4], kv[4];
#pragma unroll
    for (int i = 0; i < 4; ++i) qv[i] = Ql[tq + i][b];
#pragma unroll
    for (int j = 0; j < 4; ++j) kv[j] = KP[aq + j][b];
#pragma unroll
    for (int i = 0; i < 4; ++i)
#pragma unroll
      for (int j = 0; j < 4; ++j) S[i][j] = fmaf(qv[i], kv[j], S[i][j]);
  }
  float ps[4] = {0.f, 0.f, 0.f, 0.f};
#pragma unroll
  for (int i = 0; i < 4; ++i) {
    int t = tq + i;
    float at = cf[t], mtt = ml[t];
#pragma unroll
    for (int j = 0; j < 4; ++j) {
      int s = aq + j;
      float w = (s <= t) ? __expf(at - cf[s] + il[s] - mtt) : 0.f;
      S[i][j] *= w;
      ps[i] += S[i][j];
    }
  }
#pragma unroll
  for (int i = 0; i < 4; ++i) {
    float p = ps[i];
    p += __shfl_xor(p, 1);
    p += __shfl_xor(p, 2);
    p += __shfl_xor(p, 4);
    p += __shfl_xor(p, 8);
    ps[i] = p;
  }
  if ((tid & 15) == 0) {
#pragma unroll
    for (int i = 0; i < 4; ++i) den[tq + i] = ps[i];
  }
  __syncthreads();
#pragma unroll
  for (int i = 0; i < 4; ++i)
#pragma unroll
    for (int j = 0; j < 4; ++j) KP[tq + i][aq + j] = S[i][j];
  __syncthreads();

  float Hh[4][4], inter[4][4];
#pragma unroll
  for (int i = 0; i < 4; ++i)
#pragma unroll
    for (int j = 0; j < 4; ++j) { Hh[i][j] = 0.f; inter[i][j] = 0.f; }
  for (int s = 0; s < 64; ++s) {
    float pv[4], vv[4];
#pragma unroll
    for (int i = 0; i < 4; ++i) pv[i] = KP[tq + i][s];
#pragma unroll
    for (int j = 0; j < 4; ++j) vv[j] = Vl[s][aq + j];
#pragma unroll
    for (int i = 0; i < 4; ++i)
#pragma unroll
      for (int j = 0; j < 4; ++j) Hh[i][j] = fmaf(pv[i], vv[j], Hh[i][j]);
  }
  for (int b = 0; b < 64; ++b) {
    float qv[4], cv[4];
#pragma unroll
    for (int i = 0; i < 4; ++i) qv[i] = Ql[tq + i][b];
#pragma unroll
    for (int j = 0; j < 4; ++j) cv[j] = Cst[aq + j][b];
#pragma unroll
    for (int i = 0; i < 4; ++i)
#pragma unroll
      for (int j = 0; j < 4; ++j) inter[i][j] = fmaf(qv[i], cv[j], inter[i][j]);
  }
#pragma unroll
  for (int i = 0; i < 4; ++i) {
    int t = tq + i;
    float dt = dl[t];
    float dn = fmaf(dt, nq[t], den[t]);
    float rinv = 1.f / fmaxf(fabsf(dn), 1.f);
    const float* orow = P + (size_t)(t0 + t) * NPAD + hb + 192 + aq;
    float4 op4 = *(const float4*)orow;
    float o0 = 1.f / (1.f + __expf(-op4.x));
    float o1 = 1.f / (1.f + __expf(-op4.y));
    float o2 = 1.f / (1.f + __expf(-op4.z));
    float o3 = 1.f / (1.f + __expf(-op4.w));
    float4 st;
    st.x = o0 * (fmaf(dt, inter[i][0], Hh[i][0]) * rinv);
    st.y = o1 * (fmaf(dt, inter[i][1], Hh[i][1]) * rinv);
    st.z = o2 * (fmaf(dt, inter[i][2], Hh[i][2]) * rinv);
    st.w = o3 * (fmaf(dt, inter[i][3], Hh[i][3]) * rinv);
    *(float4*)(out + (size_t)(t0 + t) * 1024 + (h << 6) + aq) = st;
  }
}

// -------------------------------------------------------------------------
extern "C" void kernel_launch(void* const* d_in, const int* in_sizes, int n_in,
                              void* d_out, int out_size, void* d_ws, size_t ws_size,
                              hipStream_t stream) {
  const float* xs   = (const float*)d_in[0];
  const float* ifw  = (const float*)d_in[1];
  const float* ow   = (const float*)d_in[2];
  const float* kqw  = (const float*)d_in[3];
  const float* vw   = (const float*)d_in[4];
  const float* ifb  = (const float*)d_in[5];
  const float* ob   = (const float*)d_in[6];
  const float* kvqb = (const float*)d_in[7];
  float* ws   = (float*)d_ws;
  _Float16* Wph = (_Float16*)(ws + OFF_WP);
  float* bias = ws + OFF_BIAS;
  float* Pm   = ws + OFF_P;
  float* Mm   = ws + OFF_M;
  float* DC   = ws + OFF_DC;
  _Float16* Xh = (_Float16*)(ws + OFF_DC);   // alias: consumed by gemm before d1 writes DC
  float* DN   = ws + OFF_DN;
  float* DL   = ws + OFF_DL;
  float* IFc  = ws + OFF_IF;
  float* outp = (float*)d_out;

  hipLaunchKernelGGL(pack_w, dim3((NPAD * D_IN) / 256), dim3(256), 0, stream,
                     ifw, ow, kqw, vw, ifb, ob, kvqb, Wph, bias);
  hipLaunchKernelGGL(conv_x, dim3((T_LEN * D_IN / 8) / 256), dim3(256), 0, stream, xs, Xh);
  hipLaunchKernelGGL(gemm_f16, dim3(NPAD / 128, T_LEN / 128), dim3(256), 0, stream,
                     Xh, Wph, bias, Pm);
  hipLaunchKernelGGL(gemm_if, dim3(T_LEN / 8), dim3(256), 0, stream, xs, ifw, ifb, Pm, IFc);
  hipLaunchKernelGGL(mscan, dim3(NH), dim3(256), 0, stream, IFc, Mm);
  hipLaunchKernelGGL(d1_dc, dim3(NCH * NH), dim3(256), 0, stream, Pm, Mm, DC, DN, DL);
  hipLaunchKernelGGL(d2_prefix, dim3(260), dim3(256), 0, stream, DC, DN, DL);
  hipLaunchKernelGGL(d3_out, dim3(NCH * NH), dim3(256), 0, stream, Pm, Mm, DC, DN, outp);
}

// Round 5
// 324.542 us; speedup vs baseline: 3.7303x; 1.3291x over previous
//
#include <hip/hip_runtime.h>
#include <math.h>

#define T_LEN 8192
#define D_IN  1024
#define NH    16
#define NPAD  4224   // 32 (i/f all heads) + 16*256 (k,q,v,o per head) = 4128, padded
#define NCH   128    // number of 64-step chunks

typedef __attribute__((ext_vector_type(8))) _Float16 f16x8;
typedef __attribute__((ext_vector_type(4))) float f32x4;

// ---- workspace layout (float offsets) ----
static const size_t OFF_WP   = 0;                                  // Wph f16 [NPAD][1024]
static const size_t OFF_BIAS = OFF_WP + (size_t)NPAD * D_IN;       // [NPAD] f32
static const size_t OFF_P    = OFF_BIAS + NPAD;                    // [T][NPAD] f32
static const size_t OFF_M    = OFF_P + (size_t)T_LEN * NPAD;       // [T][16] f32
static const size_t OFF_DC   = OFF_M + (size_t)T_LEN * NH;         // [NCH][16][64][64] f32; ALSO aliases Xh f16 [T][1024] (consumed before DC written)
static const size_t OFF_DN   = OFF_DC + (size_t)NCH * NH * 64 * 64;// [NCH][16][64]
static const size_t OFF_DL   = OFF_DN + (size_t)NCH * NH * 64;     // [NCH][16]
static const size_t OFF_IF   = OFF_DL + (size_t)NCH * NH;          // IFc [T][32] compact i/f

__device__ __forceinline__ void glds16(const void* g, void* l) {
  __builtin_amdgcn_global_load_lds(
      (const __attribute__((address_space(1))) void*)g,
      (__attribute__((address_space(3))) void*)l, 16, 0, 0);
}

// -------------------------------------------------------------------------
// Pack weights into Wph f16 [4224][1024]; row order per head h (base 32+256h):
//   [0..64) k rows (pre-scaled by 1/8), [64..128) q, [128..192) v, [192..256) o
// rows [0..32): i/f interleaved (n=2h+t). bias fp32.
// -------------------------------------------------------------------------
__global__ __launch_bounds__(256) void pack_w(
    const float* __restrict__ ifw, const float* __restrict__ ow,
    const float* __restrict__ kqw, const float* __restrict__ vw,
    const float* __restrict__ ifb, const float* __restrict__ ob,
    const float* __restrict__ kvqb, _Float16* __restrict__ Wph, float* __restrict__ bias) {
  int idx = blockIdx.x * 256 + threadIdx.x;
  int n = idx >> 10, d = idx & 1023;
  float w = 0.f, b = 0.f;
  if (n < 32) {
    int h = n >> 1, t = n & 1;
    w = ifw[(h * 2 + t) * D_IN + d];
    b = ifb[h * 2 + t];
  } else if (n < 4128) {
    int r = n - 32;
    int h = r >> 8, j = r & 255;
    if (j < 64)       { w = kqw[(h * 128 + j) * D_IN + d] * 0.125f; b = kvqb[(h * 3 + 0) * 64 + j]; }
    else if (j < 128) { w = kqw[(h * 128 + j) * D_IN + d];          b = kvqb[(h * 3 + 2) * 64 + (j - 64)]; }
    else if (j < 192) { w = vw[(h * 64 + (j - 128)) * D_IN + d];    b = kvqb[(h * 3 + 1) * 64 + (j - 128)]; }
    else              { w = ow[(h * 64 + (j - 192)) * D_IN + d];    b = ob[h * 64 + (j - 192)]; }
  }
  Wph[(size_t)n * D_IN + d] = (_Float16)w;
  if (d == 0) bias[n] = b;
}

// -------------------------------------------------------------------------
// X fp32 -> f16
// -------------------------------------------------------------------------
__global__ __launch_bounds__(256) void conv_x(const float* __restrict__ X, _Float16* __restrict__ Xh) {
  int i = (blockIdx.x * 256 + threadIdx.x) << 3;
  float4 v0 = *(const float4*)(X + i);
  float4 v1 = *(const float4*)(X + i + 4);
  f16x8 r;
  r[0] = (_Float16)v0.x; r[1] = (_Float16)v0.y; r[2] = (_Float16)v0.z; r[3] = (_Float16)v0.w;
  r[4] = (_Float16)v1.x; r[5] = (_Float16)v1.y; r[6] = (_Float16)v1.z; r[7] = (_Float16)v1.w;
  *(f16x8*)(Xh + i) = r;
}

// -------------------------------------------------------------------------
// f16 MFMA GEMM (m97 structure): P[8192][4224] = Xh * Wph^T + bias (fp32 out)
// -------------------------------------------------------------------------
__global__ __launch_bounds__(256) void gemm_f16(
    const _Float16* __restrict__ Xh, const _Float16* __restrict__ Wph,
    const float* __restrict__ bias, float* __restrict__ P) {
  __shared__ _Float16 As[128 * 32];
  __shared__ _Float16 Bs[128 * 32];
  int tid = threadIdx.x;
  int wave = tid >> 6, lane = tid & 63;
  int m0 = blockIdx.y << 7, n0 = blockIdx.x << 7;
  int wr = wave >> 1, wc = wave & 1;

  f32x4 acc[4][4];
  f32x4 zero = {0.f, 0.f, 0.f, 0.f};
#pragma unroll
  for (int i = 0; i < 4; ++i)
#pragma unroll
    for (int j = 0; j < 4; ++j) acc[i][j] = zero;

  int srow = lane >> 2;           // 0..15
  int scol = (lane & 3) << 3;     // 0,8,16,24
  const _Float16* ga = Xh + (size_t)(m0 + wave * 32 + srow) * D_IN + scol;
  const _Float16* gb = Wph + (size_t)(n0 + wave * 32 + srow) * D_IN + scol;
  _Float16* la0 = As + (wave * 32) * 32;
  _Float16* la1 = As + (wave * 32 + 16) * 32;
  _Float16* lb0 = Bs + (wave * 32) * 32;
  _Float16* lb1 = Bs + (wave * 32 + 16) * 32;

  int fr = lane & 15;             // fragment row
  int fk = (lane >> 4) << 3;      // k offset 0,8,16,24

  for (int k0 = 0; k0 < D_IN; k0 += 32) {
    __syncthreads();
    glds16(ga + k0, la0);
    glds16(ga + 16 * D_IN + k0, la1);
    glds16(gb + k0, lb0);
    glds16(gb + 16 * D_IN + k0, lb1);
    __syncthreads();

    f16x8 a[4], b[4];
#pragma unroll
    for (int mi = 0; mi < 4; ++mi)
      a[mi] = *(const f16x8*)&As[(wr * 64 + mi * 16 + fr) * 32 + fk];
#pragma unroll
    for (int ni = 0; ni < 4; ++ni)
      b[ni] = *(const f16x8*)&Bs[(wc * 64 + ni * 16 + fr) * 32 + fk];
#pragma unroll
    for (int mi = 0; mi < 4; ++mi)
#pragma unroll
      for (int ni = 0; ni < 4; ++ni)
        acc[mi][ni] = __builtin_amdgcn_mfma_f32_16x16x32_f16(a[mi], b[ni], acc[mi][ni], 0, 0, 0);
  }

  int cr = (lane >> 4) << 2;
  int cc = lane & 15;
#pragma unroll
  for (int mi = 0; mi < 4; ++mi) {
#pragma unroll
    for (int ni = 0; ni < 4; ++ni) {
      int col = n0 + wc * 64 + ni * 16 + cc;
      float bb = bias[col];
      size_t base = (size_t)(m0 + wr * 64 + mi * 16 + cr) * NPAD + col;
#pragma unroll
      for (int r = 0; r < 4; ++r)
        P[base + (size_t)r * NPAD] = acc[mi][ni][r] + bb;
    }
  }
}

// -------------------------------------------------------------------------
// fp32 exact i/f columns, LDS-tiled: 128 blocks x 64 rows, 256 threads,
// thread = 4 rows x 2 cols. Coalesced staging + XOR-swizzled LDS
// (Xs stride 72 + sx(row)=((row>>2)&3)<<2; Ws stride 68 + sw(n)=((n>>3)&3)<<2
//  -> all compute reads <=2-way bank aliased = free).
// Writes P[:,0:32] and compact IFc[T][32].
// -------------------------------------------------------------------------
__global__ __launch_bounds__(256) void gemm_if(
    const float* __restrict__ X, const float* __restrict__ ifw,
    const float* __restrict__ ifb, float* __restrict__ P, float* __restrict__ IFc) {
  __shared__ float Xs[64 * 72];
  __shared__ float Ws[32 * 68];
  int tid = threadIdx.x;
  int r0 = blockIdx.x << 6;
  int nc = tid & 15;            // col pair: n0=2nc, n0+1
  int rg = tid >> 4;            // rows rg*4 .. rg*4+3
  int n0 = nc << 1;
  int sw = ((n0 >> 3) & 3) << 2;
  int sx = (rg & 3) << 2;       // = ((row>>2)&3)<<2 for rows rg*4+j

  float acc[4][2];
#pragma unroll
  for (int j = 0; j < 4; ++j) { acc[j][0] = 0.f; acc[j][1] = 0.f; }

  for (int k0 = 0; k0 < D_IN; k0 += 64) {
    __syncthreads();
#pragma unroll
    for (int i = 0; i < 4; ++i) {
      int fi = (i << 8) + tid;                 // 0..1023
      int row = fi >> 4, kk = (fi & 15) << 2;
      float4 v = *(const float4*)(X + (size_t)(r0 + row) * D_IN + k0 + kk);
      *(float4*)&Xs[row * 72 + (kk ^ (((row >> 2) & 3) << 2))] = v;
    }
#pragma unroll
    for (int i = 0; i < 2; ++i) {
      int fi = (i << 8) + tid;                 // 0..511
      int row = fi >> 4, kk = (fi & 15) << 2;
      float4 v = *(const float4*)(ifw + (size_t)row * D_IN + k0 + kk);
      *(float4*)&Ws[row * 68 + (kk ^ (((row >> 3) & 3) << 2))] = v;
    }
    __syncthreads();
#pragma unroll
    for (int k4 = 0; k4 < 64; k4 += 4) {
      float4 w0 = *(const float4*)&Ws[n0 * 68 + (k4 ^ sw)];
      float4 w1 = *(const float4*)&Ws[(n0 + 1) * 68 + (k4 ^ sw)];
#pragma unroll
      for (int j = 0; j < 4; ++j) {
        float4 xv = *(const float4*)&Xs[((rg << 2) + j) * 72 + (k4 ^ sx)];
        acc[j][0] = fmaf(xv.x, w0.x, acc[j][0]);
        acc[j][0] = fmaf(xv.y, w0.y, acc[j][0]);
        acc[j][0] = fmaf(xv.z, w0.z, acc[j][0]);
        acc[j][0] = fmaf(xv.w, w0.w, acc[j][0]);
        acc[j][1] = fmaf(xv.x, w1.x, acc[j][1]);
        acc[j][1] = fmaf(xv.y, w1.y, acc[j][1]);
        acc[j][1] = fmaf(xv.z, w1.z, acc[j][1]);
        acc[j][1] = fmaf(xv.w, w1.w, acc[j][1]);
      }
    }
  }
  float b0 = ifb[n0], b1 = ifb[n0 + 1];
#pragma unroll
  for (int j = 0; j < 4; ++j) {
    int row = r0 + (rg << 2) + j;
    float v0 = acc[j][0] + b0, v1 = acc[j][1] + b1;
    P[(size_t)row * NPAD + n0] = v0;
    P[(size_t)row * NPAD + n0 + 1] = v1;
    float2 st; st.x = v0; st.y = v1;
    *(float2*)(IFc + ((size_t)row << 5) + n0) = st;
  }
}

// -------------------------------------------------------------------------
// Parallel m-scan: m_t = max(f_t + m_{t-1}, i_t), m_{-1}=0.
// g_{f,i}(m)=max(m+f,i) composes as (F1,I1)o(F2,I2)=(F1+F2, max(I1+F2,I2)).
// 16 blocks (1 head) x 256 threads; 32-step segments; shfl+LDS scan.
// -------------------------------------------------------------------------
__global__ __launch_bounds__(256) void mscan(const float* __restrict__ IFc, float* __restrict__ M) {
  int h = blockIdx.x;
  int tid = threadIdx.x;
  int lane = tid & 63, wv = tid >> 6;
  int t0 = tid << 5;
  // phase 1: compose own 32-step segment
  float F = 0.f, I = -1e30f;
#pragma unroll 8
  for (int u = 0; u < 32; ++u) {
    float2 v = *(const float2*)(IFc + ((size_t)(t0 + u) << 5) + (h << 1));
    I = fmaxf(I + v.y, v.x);
    F += v.y;
  }
  // phase 2a: wave-level inclusive scan (non-commutative compose)
#pragma unroll
  for (int d = 1; d < 64; d <<= 1) {
    float Fo = __shfl_up(F, d, 64);
    float Io = __shfl_up(I, d, 64);
    if (lane >= d) { I = fmaxf(Io + F, I); F = Fo + F; }
  }
  __shared__ float sF[4], sI[4];
  if (lane == 63) { sF[wv] = F; sI[wv] = I; }
  // exclusive within wave
  float Fe = __shfl_up(F, 1, 64);
  float Ie = __shfl_up(I, 1, 64);
  if (lane == 0) { Fe = 0.f; Ie = -1e30f; }
  __syncthreads();
  // phase 2b: compose aggregates of previous waves
  float Fp = 0.f, Ip = -1e30f;
  for (int w = 0; w < wv; ++w) { Ip = fmaxf(Ip + sF[w], sI[w]); Fp += sF[w]; }
  float Ft = Fp + Fe;
  float It = fmaxf(Ip + Fe, Ie);
  float m = fmaxf(Ft, It);   // prefix applied to m_{-1}=0
  // phase 3: replay segment with incoming prefix
#pragma unroll 8
  for (int u = 0; u < 32; ++u) {
    float2 v = *(const float2*)(IFc + ((size_t)(t0 + u) << 5) + (h << 1));
    m = fmaxf(v.y + m, v.x);
    M[(size_t)(t0 + u) * NH + h] = m;
  }
}

// -------------------------------------------------------------------------
// D1: per (chunk,head): DC = sum_s g_s v_s k_s^T,  DN = sum_s g_s k_s,
//     DL = chunk decay,  with g_s = exp(cumF_L - cumF_s + i_s - m_L).
// -------------------------------------------------------------------------
__global__ __launch_bounds__(256) void d1_dc(
    const float* __restrict__ P, const float* __restrict__ M,
    float* __restrict__ DC, float* __restrict__ DN, float* __restrict__ DL) {
  int c = blockIdx.x >> 4, h = blockIdx.x & 15;
  int t0 = c << 6, hb = 32 + (h << 8);
  int tid = threadIdx.x;
  __shared__ float Kl[64][65];
  __shared__ float Vl[64][65];
  __shared__ float gl[64];
#pragma unroll
  for (int i = 0; i < 4; ++i) {
    int fq = (i << 8) + tid;
    int s = fq >> 4, b4 = (fq & 15) << 2;
    const float* row = P + (size_t)(t0 + s) * NPAD + hb;
    float4 kv = *(const float4*)(row + b4);
    float4 vv = *(const float4*)(row + 128 + b4);
    Kl[s][b4 + 0] = kv.x; Kl[s][b4 + 1] = kv.y; Kl[s][b4 + 2] = kv.z; Kl[s][b4 + 3] = kv.w;
    Vl[s][b4 + 0] = vv.x; Vl[s][b4 + 1] = vv.y; Vl[s][b4 + 2] = vv.z; Vl[s][b4 + 3] = vv.w;
  }
  if (tid < 64) {
    float2 iff = *(const float2*)(P + (size_t)(t0 + tid) * NPAD + (h << 1));
    float iv = iff.x, fv = iff.y;
    float cs = fv;
#pragma unroll
    for (int dd = 1; dd < 64; dd <<= 1) {
      float o = __shfl_up(cs, dd, 64);
      cs += (tid >= dd) ? o : 0.f;
    }
    float cumL = __shfl(cs, 63, 64);
    float mL = M[(size_t)(t0 + 63) * NH + h];
    gl[tid] = __expf(cumL - cs + iv - mL);
    if (tid == 0) {
      float mstart = (c > 0) ? M[(size_t)(t0 - 1) * NH + h] : 0.f;
      DL[(c << 4) + h] = __expf(mstart + cumL - mL);
    }
  }
  __syncthreads();
  if (tid < 64) {
    float acc = 0.f;
#pragma unroll
    for (int s = 0; s < 64; ++s) acc = fmaf(gl[s], Kl[s][tid], acc);
    DN[((size_t)(c << 4) + h) * 64 + tid] = acc;
  }
  int a = tid & 63, bq = tid >> 6;
  float acc[16];
#pragma unroll
  for (int j = 0; j < 16; ++j) acc[j] = 0.f;
  for (int s = 0; s < 64; ++s) {
    float gv = gl[s] * Vl[s][a];
#pragma unroll
    for (int j = 0; j < 16; ++j) acc[j] = fmaf(gv, Kl[s][(bq << 4) + j], acc[j]);
  }
  size_t base = (((size_t)(c << 4) + h) << 12) + ((size_t)a << 6) + (bq << 4);
#pragma unroll
  for (int j4 = 0; j4 < 16; j4 += 4) {
    float4 st; st.x = acc[j4]; st.y = acc[j4 + 1]; st.z = acc[j4 + 2]; st.w = acc[j4 + 3];
    *(float4*)(DC + base + j4) = st;
  }
}

// -------------------------------------------------------------------------
// D2: in-place weighted prefix over chunks.
// -------------------------------------------------------------------------
__global__ __launch_bounds__(256) void d2_prefix(
    float* __restrict__ DC, float* __restrict__ DN, const float* __restrict__ DL) {
  int bid = blockIdx.x, tid = threadIdx.x;
  if (bid < 256) {
    int e = (bid << 8) + tid;
    int h = e >> 12, pos = e & 4095;
    float carry = 0.f;
    size_t idx = ((size_t)h << 12) + pos;
    float v = DC[idx];
    for (int c = 0; c < NCH; ++c) {
      float dl = DL[(c << 4) + h];
      float vn = (c < NCH - 1) ? DC[idx + 65536] : 0.f;
      DC[idx] = carry;
      carry = fmaf(dl, carry, v);
      v = vn;
      idx += 65536;
    }
  } else {
    int e = ((bid - 256) << 8) + tid;
    int h = e >> 6, b = e & 63;
    float carry = 0.f;
    size_t idx = ((size_t)h << 6) + b;
    float v = DN[idx];
    for (int c = 0; c < NCH; ++c) {
      float dl = DL[(c << 4) + h];
      float vn = (c < NCH - 1) ? DN[idx + 1024] : 0.f;
      DN[idx] = carry;
      carry = fmaf(dl, carry, v);
      v = vn;
      idx += 1024;
    }
  }
}

// -------------------------------------------------------------------------
// D3: per (chunk,head) outputs.
// -------------------------------------------------------------------------
__global__ __launch_bounds__(256) void d3_out(
    const float* __restrict__ P, const float* __restrict__ M,
    const float* __restrict__ CS, const float* __restrict__ NS,
    float* __restrict__ out) {
  int c = blockIdx.x >> 4, h = blockIdx.x & 15;
  int t0 = c << 6, hb = 32 + (h << 8);
  int tid = threadIdx.x;
  __shared__ float KP[64][65];   // K, later overwritten with P=W.*S
  __shared__ float Ql[64][65];
  __shared__ float Vl[64][65];
  __shared__ float Cst[64][65];
  __shared__ float cf[64], il[64], ml[64], dl[64], nq[64], den[64], nsl[64];
#pragma unroll
  for (int i = 0; i < 4; ++i) {
    int fq = (i << 8) + tid;
    int s = fq >> 4, b4 = (fq & 15) << 2;
    const float* row = P + (size_t)(t0 + s) * NPAD + hb;
    float4 kv = *(const float4*)(row + b4);
    float4 qv = *(const float4*)(row + 64 + b4);
    float4 vv = *(const float4*)(row + 128 + b4);
    float4 cv = *(const float4*)(CS + ((((size_t)(c << 4)) + h) << 12) + ((size_t)s << 6) + b4);
    KP[s][b4 + 0] = kv.x; KP[s][b4 + 1] = kv.y; KP[s][b4 + 2] = kv.z; KP[s][b4 + 3] = kv.w;
    Ql[s][b4 + 0] = qv.x; Ql[s][b4 + 1] = qv.y; Ql[s][b4 + 2] = qv.z; Ql[s][b4 + 3] = qv.w;
    Vl[s][b4 + 0] = vv.x; Vl[s][b4 + 1] = vv.y; Vl[s][b4 + 2] = vv.z; Vl[s][b4 + 3] = vv.w;
    Cst[s][b4 + 0] = cv.x; Cst[s][b4 + 1] = cv.y; Cst[s][b4 + 2] = cv.z; Cst[s][b4 + 3] = cv.w;
  }
  float iv = 0.f, mt = 0.f, cs = 0.f;
  if (tid < 64) {
    float2 iff = *(const float2*)(P + (size_t)(t0 + tid) * NPAD + (h << 1));
    iv = iff.x;
    float fv = iff.y;
    mt = M[(size_t)(t0 + tid) * NH + h];
    nsl[tid] = NS[((size_t)(c << 4) + h) * 64 + tid];
    cs = fv;
#pragma unroll
    for (int dd = 1; dd < 64; dd <<= 1) {
      float o = __shfl_up(cs, dd, 64);
      cs += (tid >= dd) ? o : 0.f;
    }
  }
  __syncthreads();
  if (tid < 64) {
    cf[tid] = cs; il[tid] = iv; ml[tid] = mt;
    float mstart = (c > 0) ? M[(size_t)(t0 - 1) * NH + h] : 0.f;
    dl[tid] = __expf(mstart + cs - mt);
    float acc = 0.f;
#pragma unroll
    for (int b = 0; b < 64; ++b) acc = fmaf(nsl[b], Ql[tid][b], acc);
    nq[tid] = acc;
  }
  __syncthreads();

  int tq = (tid >> 4) << 2;
  int aq = (tid & 15) << 2;
  float S[4][4];
#pragma unroll
  for (int i = 0; i < 4; ++i)
#pragma unroll
    for (int j = 0; j < 4; ++j) S[i][j] = 0.f;
  for (int b = 0; b < 64; ++b) {
    float qv[4], kv[4];
#pragma unroll
    for (int i = 0; i < 4; ++i) qv[i] = Ql[tq + i][b];
#pragma unroll
    for (int j = 0; j < 4; ++j) kv[j] = KP[aq + j][b];
#pragma unroll
    for (int i = 0; i < 4; ++i)
#pragma unroll
      for (int j = 0; j < 4; ++j) S[i][j] = fmaf(qv[i], kv[j], S[i][j]);
  }
  float ps[4] = {0.f, 0.f, 0.f, 0.f};
#pragma unroll
  for (int i = 0; i < 4; ++i) {
    int t = tq + i;
    float at = cf[t], mtt = ml[t];
#pragma unroll
    for (int j = 0; j < 4; ++j) {
      int s = aq + j;
      float w = (s <= t) ? __expf(at - cf[s] + il[s] - mtt) : 0.f;
      S[i][j] *= w;
      ps[i] += S[i][j];
    }
  }
#pragma unroll
  for (int i = 0; i < 4; ++i) {
    float p = ps[i];
    p += __shfl_xor(p, 1);
    p += __shfl_xor(p, 2);
    p += __shfl_xor(p, 4);
    p += __shfl_xor(p, 8);
    ps[i] = p;
  }
  if ((tid & 15) == 0) {
#pragma unroll
    for (int i = 0; i < 4; ++i) den[tq + i] = ps[i];
  }
  __syncthreads();
#pragma unroll
  for (int i = 0; i < 4; ++i)
#pragma unroll
    for (int j = 0; j < 4; ++j) KP[tq + i][aq + j] = S[i][j];
  __syncthreads();

  float Hh[4][4], inter[4][4];
#pragma unroll
  for (int i = 0; i < 4; ++i)
#pragma unroll
    for (int j = 0; j < 4; ++j) { Hh[i][j] = 0.f; inter[i][j] = 0.f; }
  for (int s = 0; s < 64; ++s) {
    float pv[4], vv[4];
#pragma unroll
    for (int i = 0; i < 4; ++i) pv[i] = KP[tq + i][s];
#pragma unroll
    for (int j = 0; j < 4; ++j) vv[j] = Vl[s][aq + j];
#pragma unroll
    for (int i = 0; i < 4; ++i)
#pragma unroll
      for (int j = 0; j < 4; ++j) Hh[i][j] = fmaf(pv[i], vv[j], Hh[i][j]);
  }
  for (int b = 0; b < 64; ++b) {
    float qv[4], cv[4];
#pragma unroll
    for (int i = 0; i < 4; ++i) qv[i] = Ql[tq + i][b];
#pragma unroll
    for (int j = 0; j < 4; ++j) cv[j] = Cst[aq + j][b];
#pragma unroll
    for (int i = 0; i < 4; ++i)
#pragma unroll
      for (int j = 0; j < 4; ++j) inter[i][j] = fmaf(qv[i], cv[j], inter[i][j]);
  }
#pragma unroll
  for (int i = 0; i < 4; ++i) {
    int t = tq + i;
    float dt = dl[t];
    float dn = fmaf(dt, nq[t], den[t]);
    float rinv = 1.f / fmaxf(fabsf(dn), 1.f);
    const float* orow = P + (size_t)(t0 + t) * NPAD + hb + 192 + aq;
    float4 op4 = *(const float4*)orow;
    float o0 = 1.f / (1.f + __expf(-op4.x));
    float o1 = 1.f / (1.f + __expf(-op4.y));
    float o2 = 1.f / (1.f + __expf(-op4.z));
    float o3 = 1.f / (1.f + __expf(-op4.w));
    float4 st;
    st.x = o0 * (fmaf(dt, inter[i][0], Hh[i][0]) * rinv);
    st.y = o1 * (fmaf(dt, inter[i][1], Hh[i][1]) * rinv);
    st.z = o2 * (fmaf(dt, inter[i][2], Hh[i][2]) * rinv);
    st.w = o3 * (fmaf(dt, inter[i][3], Hh[i][3]) * rinv);
    *(float4*)(out + (size_t)(t0 + t) * 1024 + (h << 6) + aq) = st;
  }
}

// -------------------------------------------------------------------------
extern "C" void kernel_launch(void* const* d_in, const int* in_sizes, int n_in,
                              void* d_out, int out_size, void* d_ws, size_t ws_size,
                              hipStream_t stream) {
  const float* xs   = (const float*)d_in[0];
  const float* ifw  = (const float*)d_in[1];
  const float* ow   = (const float*)d_in[2];
  const float* kqw  = (const float*)d_in[3];
  const float* vw   = (const float*)d_in[4];
  const float* ifb  = (const float*)d_in[5];
  const float* ob   = (const float*)d_in[6];
  const float* kvqb = (const float*)d_in[7];
  float* ws   = (float*)d_ws;
  _Float16* Wph = (_Float16*)(ws + OFF_WP);
  float* bias = ws + OFF_BIAS;
  float* Pm   = ws + OFF_P;
  float* Mm   = ws + OFF_M;
  float* DC   = ws + OFF_DC;
  _Float16* Xh = (_Float16*)(ws + OFF_DC);   // alias: consumed by gemm before d1 writes DC
  float* DN   = ws + OFF_DN;
  float* DL   = ws + OFF_DL;
  float* IFc  = ws + OFF_IF;
  float* outp = (float*)d_out;

  hipLaunchKernelGGL(pack_w, dim3((NPAD * D_IN) / 256), dim3(256), 0, stream,
                     ifw, ow, kqw, vw, ifb, ob, kvqb, Wph, bias);
  hipLaunchKernelGGL(conv_x, dim3((T_LEN * D_IN / 8) / 256), dim3(256), 0, stream, xs, Xh);
  hipLaunchKernelGGL(gemm_f16, dim3(NPAD / 128, T_LEN / 128), dim3(256), 0, stream,
                     Xh, Wph, bias, Pm);
  hipLaunchKernelGGL(gemm_if, dim3(T_LEN / 64), dim3(256), 0, stream, xs, ifw, ifb, Pm, IFc);
  hipLaunchKernelGGL(mscan, dim3(NH), dim3(256), 0, stream, IFc, Mm);
  hipLaunchKernelGGL(d1_dc, dim3(NCH * NH), dim3(256), 0, stream, Pm, Mm, DC, DN, DL);
  hipLaunchKernelGGL(d2_prefix, dim3(260), dim3(256), 0, stream, DC, DN, DL);
  hipLaunchKernelGGL(d3_out, dim3(NCH * NH), dim3(256), 0, stream, Pm, Mm, DC, DN, outp);
}

// Round 6
// 302.685 us; speedup vs baseline: 3.9996x; 1.0722x over previous
//
#include <hip/hip_runtime.h>
#include <math.h>

#define T_LEN 8192
#define D_IN  1024
#define NH    16
#define NPAD  4224   // 32 (i/f, unused cols) + 16*256 (k,q,v,o per head), padded
#define NCH   128    // number of 64-step chunks
#define NGRP  8      // chunk groups for d2 scan
#define GSZ   16     // chunks per group

typedef __attribute__((ext_vector_type(8))) _Float16 f16x8;
typedef __attribute__((ext_vector_type(4))) _Float16 f16x4;
typedef __attribute__((ext_vector_type(4))) float f32x4;

// ---- workspace layout (float offsets) ----
static const size_t OFF_WP   = 0;                                  // Wph f16 [NPAD][1024] (uses 2.163M floats of 4.33M)
static const size_t OFF_BG   = 2300000;                            // Bg_dc [8][65536] + Bg_dn [8][1024] + Ag [8][16] (in Wph region tail)
static const size_t OFF_BIAS = OFF_WP + (size_t)NPAD * D_IN;       // [NPAD] f32
static const size_t OFF_P    = OFF_BIAS + NPAD;                    // Ph f16 [T][NPAD] (uses half the f32-sized region)
static const size_t OFF_M    = OFF_P + (size_t)T_LEN * NPAD;       // [T][16] f32
static const size_t OFF_DC   = OFF_M + (size_t)T_LEN * NH;         // [NCH][16][64][64] f32; ALSO aliases Xh f16 (consumed before DC written)
static const size_t OFF_DN   = OFF_DC + (size_t)NCH * NH * 64 * 64;// [NCH][16][64]
static const size_t OFF_DL   = OFF_DN + (size_t)NCH * NH * 64;     // [NCH][16]
static const size_t OFF_IF   = OFF_DL + (size_t)NCH * NH;          // IFc [T][32] compact i/f (fp32)

__device__ __forceinline__ void glds16(const void* g, void* l) {
  __builtin_amdgcn_global_load_lds(
      (const __attribute__((address_space(1))) void*)g,
      (__attribute__((address_space(3))) void*)l, 16, 0, 0);
}

// -------------------------------------------------------------------------
// Pack weights into Wph f16 [4224][1024]; per head h (base 32+256h):
//   [0..64) k (pre-scaled 1/8), [64..128) q, [128..192) v, [192..256) o
// -------------------------------------------------------------------------
__global__ __launch_bounds__(256) void pack_w(
    const float* __restrict__ ifw, const float* __restrict__ ow,
    const float* __restrict__ kqw, const float* __restrict__ vw,
    const float* __restrict__ ifb, const float* __restrict__ ob,
    const float* __restrict__ kvqb, _Float16* __restrict__ Wph, float* __restrict__ bias) {
  int idx = blockIdx.x * 256 + threadIdx.x;
  int n = idx >> 10, d = idx & 1023;
  float w = 0.f, b = 0.f;
  if (n < 32) {
    int h = n >> 1, t = n & 1;
    w = ifw[(h * 2 + t) * D_IN + d];
    b = ifb[h * 2 + t];
  } else if (n < 4128) {
    int r = n - 32;
    int h = r >> 8, j = r & 255;
    if (j < 64)       { w = kqw[(h * 128 + j) * D_IN + d] * 0.125f; b = kvqb[(h * 3 + 0) * 64 + j]; }
    else if (j < 128) { w = kqw[(h * 128 + j) * D_IN + d];          b = kvqb[(h * 3 + 2) * 64 + (j - 64)]; }
    else if (j < 192) { w = vw[(h * 64 + (j - 128)) * D_IN + d];    b = kvqb[(h * 3 + 1) * 64 + (j - 128)]; }
    else              { w = ow[(h * 64 + (j - 192)) * D_IN + d];    b = ob[h * 64 + (j - 192)]; }
  }
  Wph[(size_t)n * D_IN + d] = (_Float16)w;
  if (d == 0) bias[n] = b;
}

// -------------------------------------------------------------------------
// X fp32 -> f16
// -------------------------------------------------------------------------
__global__ __launch_bounds__(256) void conv_x(const float* __restrict__ X, _Float16* __restrict__ Xh) {
  int i = (blockIdx.x * 256 + threadIdx.x) << 3;
  float4 v0 = *(const float4*)(X + i);
  float4 v1 = *(const float4*)(X + i + 4);
  f16x8 r;
  r[0] = (_Float16)v0.x; r[1] = (_Float16)v0.y; r[2] = (_Float16)v0.z; r[3] = (_Float16)v0.w;
  r[4] = (_Float16)v1.x; r[5] = (_Float16)v1.y; r[6] = (_Float16)v1.z; r[7] = (_Float16)v1.w;
  *(f16x8*)(Xh + i) = r;
}

// -------------------------------------------------------------------------
// f16 MFMA GEMM: Ph[8192][4224](f16) = Xh * Wph^T + bias.
// m97 structure + XCD-chunked swizzle (nwg=2112=8*264, m-major per XCD).
// -------------------------------------------------------------------------
__global__ __launch_bounds__(256) void gemm_f16(
    const _Float16* __restrict__ Xh, const _Float16* __restrict__ Wph,
    const float* __restrict__ bias, _Float16* __restrict__ Ph) {
  __shared__ _Float16 As[128 * 32];
  __shared__ _Float16 Bs[128 * 32];
  int tid = threadIdx.x;
  int wave = tid >> 6, lane = tid & 63;
  // swizzle: consecutive hw blocks round-robin XCDs; give each XCD a
  // contiguous m-major span so Wph panels + Xh tiles stay L2-local.
  int wgid = blockIdx.x;
  int virt = (wgid & 7) * 264 + (wgid >> 3);
  int mt = virt / 33, nt = virt % 33;
  int m0 = mt << 7, n0 = nt << 7;
  int wr = wave >> 1, wc = wave & 1;

  f32x4 acc[4][4];
  f32x4 zero = {0.f, 0.f, 0.f, 0.f};
#pragma unroll
  for (int i = 0; i < 4; ++i)
#pragma unroll
    for (int j = 0; j < 4; ++j) acc[i][j] = zero;

  int srow = lane >> 2;           // 0..15
  int scol = (lane & 3) << 3;     // 0,8,16,24
  const _Float16* ga = Xh + (size_t)(m0 + wave * 32 + srow) * D_IN + scol;
  const _Float16* gb = Wph + (size_t)(n0 + wave * 32 + srow) * D_IN + scol;
  _Float16* la0 = As + (wave * 32) * 32;
  _Float16* la1 = As + (wave * 32 + 16) * 32;
  _Float16* lb0 = Bs + (wave * 32) * 32;
  _Float16* lb1 = Bs + (wave * 32 + 16) * 32;

  int fr = lane & 15;
  int fk = (lane >> 4) << 3;

  for (int k0 = 0; k0 < D_IN; k0 += 32) {
    __syncthreads();
    glds16(ga + k0, la0);
    glds16(ga + 16 * D_IN + k0, la1);
    glds16(gb + k0, lb0);
    glds16(gb + 16 * D_IN + k0, lb1);
    __syncthreads();

    f16x8 a[4], b[4];
#pragma unroll
    for (int mi = 0; mi < 4; ++mi)
      a[mi] = *(const f16x8*)&As[(wr * 64 + mi * 16 + fr) * 32 + fk];
#pragma unroll
    for (int ni = 0; ni < 4; ++ni)
      b[ni] = *(const f16x8*)&Bs[(wc * 64 + ni * 16 + fr) * 32 + fk];
#pragma unroll
    for (int mi = 0; mi < 4; ++mi)
#pragma unroll
      for (int ni = 0; ni < 4; ++ni)
        acc[mi][ni] = __builtin_amdgcn_mfma_f32_16x16x32_f16(a[mi], b[ni], acc[mi][ni], 0, 0, 0);
  }

  int cr = (lane >> 4) << 2;
  int cc = lane & 15;
#pragma unroll
  for (int mi = 0; mi < 4; ++mi) {
#pragma unroll
    for (int ni = 0; ni < 4; ++ni) {
      int col = n0 + wc * 64 + ni * 16 + cc;
      float bb = bias[col];
      size_t base = (size_t)(m0 + wr * 64 + mi * 16 + cr) * NPAD + col;
#pragma unroll
      for (int r = 0; r < 4; ++r)
        Ph[base + (size_t)r * NPAD] = (_Float16)(acc[mi][ni][r] + bb);
    }
  }
}

// -------------------------------------------------------------------------
// fp32 exact i/f columns, LDS-tiled -> IFc[T][32] only.
// -------------------------------------------------------------------------
__global__ __launch_bounds__(256) void gemm_if(
    const float* __restrict__ X, const float* __restrict__ ifw,
    const float* __restrict__ ifb, float* __restrict__ IFc) {
  __shared__ float Xs[64 * 72];
  __shared__ float Ws[32 * 68];
  int tid = threadIdx.x;
  int r0 = blockIdx.x << 6;
  int nc = tid & 15;
  int rg = tid >> 4;
  int n0 = nc << 1;
  int sw = ((n0 >> 3) & 3) << 2;
  int sx = (rg & 3) << 2;

  float acc[4][2];
#pragma unroll
  for (int j = 0; j < 4; ++j) { acc[j][0] = 0.f; acc[j][1] = 0.f; }

  for (int k0 = 0; k0 < D_IN; k0 += 64) {
    __syncthreads();
#pragma unroll
    for (int i = 0; i < 4; ++i) {
      int fi = (i << 8) + tid;
      int row = fi >> 4, kk = (fi & 15) << 2;
      float4 v = *(const float4*)(X + (size_t)(r0 + row) * D_IN + k0 + kk);
      *(float4*)&Xs[row * 72 + (kk ^ (((row >> 2) & 3) << 2))] = v;
    }
#pragma unroll
    for (int i = 0; i < 2; ++i) {
      int fi = (i << 8) + tid;
      int row = fi >> 4, kk = (fi & 15) << 2;
      float4 v = *(const float4*)(ifw + (size_t)row * D_IN + k0 + kk);
      *(float4*)&Ws[row * 68 + (kk ^ (((row >> 3) & 3) << 2))] = v;
    }
    __syncthreads();
#pragma unroll
    for (int k4 = 0; k4 < 64; k4 += 4) {
      float4 w0 = *(const float4*)&Ws[n0 * 68 + (k4 ^ sw)];
      float4 w1 = *(const float4*)&Ws[(n0 + 1) * 68 + (k4 ^ sw)];
#pragma unroll
      for (int j = 0; j < 4; ++j) {
        float4 xv = *(const float4*)&Xs[((rg << 2) + j) * 72 + (k4 ^ sx)];
        acc[j][0] = fmaf(xv.x, w0.x, acc[j][0]);
        acc[j][0] = fmaf(xv.y, w0.y, acc[j][0]);
        acc[j][0] = fmaf(xv.z, w0.z, acc[j][0]);
        acc[j][0] = fmaf(xv.w, w0.w, acc[j][0]);
        acc[j][1] = fmaf(xv.x, w1.x, acc[j][1]);
        acc[j][1] = fmaf(xv.y, w1.y, acc[j][1]);
        acc[j][1] = fmaf(xv.z, w1.z, acc[j][1]);
        acc[j][1] = fmaf(xv.w, w1.w, acc[j][1]);
      }
    }
  }
  float b0 = ifb[n0], b1 = ifb[n0 + 1];
#pragma unroll
  for (int j = 0; j < 4; ++j) {
    int row = r0 + (rg << 2) + j;
    float2 st; st.x = acc[j][0] + b0; st.y = acc[j][1] + b1;
    *(float2*)(IFc + ((size_t)row << 5) + n0) = st;
  }
}

// -------------------------------------------------------------------------
// Parallel m-scan (associative (max,+) compose), 16 blocks x 256 threads.
// -------------------------------------------------------------------------
__global__ __launch_bounds__(256) void mscan(const float* __restrict__ IFc, float* __restrict__ M) {
  int h = blockIdx.x;
  int tid = threadIdx.x;
  int lane = tid & 63, wv = tid >> 6;
  int t0 = tid << 5;
  float F = 0.f, I = -1e30f;
#pragma unroll 8
  for (int u = 0; u < 32; ++u) {
    float2 v = *(const float2*)(IFc + ((size_t)(t0 + u) << 5) + (h << 1));
    I = fmaxf(I + v.y, v.x);
    F += v.y;
  }
#pragma unroll
  for (int d = 1; d < 64; d <<= 1) {
    float Fo = __shfl_up(F, d, 64);
    float Io = __shfl_up(I, d, 64);
    if (lane >= d) { I = fmaxf(Io + F, I); F = Fo + F; }
  }
  __shared__ float sF[4], sI[4];
  if (lane == 63) { sF[wv] = F; sI[wv] = I; }
  float Fe = __shfl_up(F, 1, 64);
  float Ie = __shfl_up(I, 1, 64);
  if (lane == 0) { Fe = 0.f; Ie = -1e30f; }
  __syncthreads();
  float Fp = 0.f, Ip = -1e30f;
  for (int w = 0; w < wv; ++w) { Ip = fmaxf(Ip + sF[w], sI[w]); Fp += sF[w]; }
  float Ft = Fp + Fe;
  float It = fmaxf(Ip + Fe, Ie);
  float m = fmaxf(Ft, It);
#pragma unroll 8
  for (int u = 0; u < 32; ++u) {
    float2 v = *(const float2*)(IFc + ((size_t)(t0 + u) << 5) + (h << 1));
    m = fmaxf(v.y + m, v.x);
    M[(size_t)(t0 + u) * NH + h] = m;
  }
}

// -------------------------------------------------------------------------
// D1: per (chunk,head): DC = sum_s g_s v_s k_s^T, DN = sum_s g_s k_s, DL.
// K/V staged from f16 Ph; i/f from fp32 IFc.
// -------------------------------------------------------------------------
__global__ __launch_bounds__(256) void d1_dc(
    const _Float16* __restrict__ Ph, const float* __restrict__ IFc,
    const float* __restrict__ M,
    float* __restrict__ DC, float* __restrict__ DN, float* __restrict__ DL) {
  int c = blockIdx.x >> 4, h = blockIdx.x & 15;
  int t0 = c << 6, hb = 32 + (h << 8);
  int tid = threadIdx.x;
  __shared__ float Kl[64][65];
  __shared__ float Vl[64][65];
  __shared__ float gl[64];
#pragma unroll
  for (int i = 0; i < 2; ++i) {
    int fq = (i << 8) + tid;              // 0..511
    int s = fq >> 3, b8 = (fq & 7) << 3;
    const _Float16* row = Ph + (size_t)(t0 + s) * NPAD + hb;
    f16x8 kv = *(const f16x8*)(row + b8);
    f16x8 vv = *(const f16x8*)(row + 128 + b8);
#pragma unroll
    for (int j = 0; j < 8; ++j) {
      Kl[s][b8 + j] = (float)kv[j];
      Vl[s][b8 + j] = (float)vv[j];
    }
  }
  if (tid < 64) {
    float2 iff = *(const float2*)(IFc + ((size_t)(t0 + tid) << 5) + (h << 1));
    float iv = iff.x, fv = iff.y;
    float cs = fv;
#pragma unroll
    for (int dd = 1; dd < 64; dd <<= 1) {
      float o = __shfl_up(cs, dd, 64);
      cs += (tid >= dd) ? o : 0.f;
    }
    float cumL = __shfl(cs, 63, 64);
    float mL = M[(size_t)(t0 + 63) * NH + h];
    gl[tid] = __expf(cumL - cs + iv - mL);
    if (tid == 0) {
      float mstart = (c > 0) ? M[(size_t)(t0 - 1) * NH + h] : 0.f;
      DL[(c << 4) + h] = __expf(mstart + cumL - mL);
    }
  }
  __syncthreads();
  if (tid < 64) {
    float acc = 0.f;
#pragma unroll
    for (int s = 0; s < 64; ++s) acc = fmaf(gl[s], Kl[s][tid], acc);
    DN[((size_t)(c << 4) + h) * 64 + tid] = acc;
  }
  int a = tid & 63, bq = tid >> 6;
  float acc[16];
#pragma unroll
  for (int j = 0; j < 16; ++j) acc[j] = 0.f;
  for (int s = 0; s < 64; ++s) {
    float gv = gl[s] * Vl[s][a];
#pragma unroll
    for (int j = 0; j < 16; ++j) acc[j] = fmaf(gv, Kl[s][(bq << 4) + j], acc[j]);
  }
  size_t base = (((size_t)(c << 4) + h) << 12) + ((size_t)a << 6) + (bq << 4);
#pragma unroll
  for (int j4 = 0; j4 < 16; j4 += 4) {
    float4 st; st.x = acc[j4]; st.y = acc[j4 + 1]; st.z = acc[j4 + 2]; st.w = acc[j4 + 3];
    *(float4*)(DC + base + j4) = st;
  }
}

// -------------------------------------------------------------------------
// D2a: per (group, elem) compute affine (A = prod dl, B = local apply-to-0)
// over the group's 16 chunks. 8x parallelism vs old d2; chain length 16.
// -------------------------------------------------------------------------
__global__ __launch_bounds__(256) void d2a(
    const float* __restrict__ DC, const float* __restrict__ DN,
    const float* __restrict__ DL,
    float* __restrict__ BgDC, float* __restrict__ BgDN, float* __restrict__ Ag) {
  int bid = blockIdx.x, tid = threadIdx.x;
  if (bid < 2048) {
    int linear = (bid << 8) + tid;        // 0..524287
    int g = linear >> 16, e = linear & 65535;
    int h = e >> 12;
    float carry = 0.f, a = 1.f;
    size_t idx = (size_t)e + ((size_t)g << 4) * 65536;
    float v = DC[idx];
    for (int u = 0; u < GSZ; ++u) {
      float dl = DL[(((g << 4) + u) << 4) + h];
      float vn = (u < GSZ - 1) ? DC[idx + 65536] : 0.f;
      carry = fmaf(dl, carry, v);
      a *= dl;
      v = vn;
      idx += 65536;
    }
    BgDC[((size_t)g << 16) + e] = carry;
    if ((e & 4095) == 0) Ag[(g << 4) + h] = a;
  } else {
    int linear = ((bid - 2048) << 8) + tid;  // 0..8191
    int g = linear >> 10, e = linear & 1023;
    int h = e >> 6;
    float carry = 0.f;
    size_t idx = (size_t)e + ((size_t)g << 4) * 1024;
    float v = DN[idx];
    for (int u = 0; u < GSZ; ++u) {
      float dl = DL[(((g << 4) + u) << 4) + h];
      float vn = (u < GSZ - 1) ? DN[idx + 1024] : 0.f;
      carry = fmaf(dl, carry, v);
      v = vn;
      idx += 1024;
    }
    BgDN[(g << 10) + e] = carry;
  }
}

// -------------------------------------------------------------------------
// D2c: inline exclusive group-prefix (<=7 affine folds) then apply within
// group, writing exclusive carries in place.
// -------------------------------------------------------------------------
__global__ __launch_bounds__(256) void d2c(
    float* __restrict__ DC, float* __restrict__ DN,
    const float* __restrict__ DL,
    const float* __restrict__ BgDC, const float* __restrict__ BgDN,
    const float* __restrict__ Ag) {
  int bid = blockIdx.x, tid = threadIdx.x;
  if (bid < 2048) {
    int linear = (bid << 8) + tid;
    int g = linear >> 16, e = linear & 65535;
    int h = e >> 12;
    float P = 0.f;
    for (int gp = 0; gp < g; ++gp)
      P = fmaf(Ag[(gp << 4) + h], P, BgDC[((size_t)gp << 16) + e]);
    float carry = P;
    size_t idx = (size_t)e + ((size_t)g << 4) * 65536;
    float v = DC[idx];
    for (int u = 0; u < GSZ; ++u) {
      float dl = DL[(((g << 4) + u) << 4) + h];
      float vn = (u < GSZ - 1) ? DC[idx + 65536] : 0.f;
      DC[idx] = carry;
      carry = fmaf(dl, carry, v);
      v = vn;
      idx += 65536;
    }
  } else {
    int linear = ((bid - 2048) << 8) + tid;
    int g = linear >> 10, e = linear & 1023;
    int h = e >> 6;
    float P = 0.f;
    for (int gp = 0; gp < g; ++gp)
      P = fmaf(Ag[(gp << 4) + h], P, BgDN[(gp << 10) + e]);
    float carry = P;
    size_t idx = (size_t)e + ((size_t)g << 4) * 1024;
    float v = DN[idx];
    for (int u = 0; u < GSZ; ++u) {
      float dl = DL[(((g << 4) + u) << 4) + h];
      float vn = (u < GSZ - 1) ? DN[idx + 1024] : 0.f;
      DN[idx] = carry;
      carry = fmaf(dl, carry, v);
      v = vn;
      idx += 1024;
    }
  }
}

// -------------------------------------------------------------------------
// D3: per (chunk,head) outputs. K/Q/V/O from f16 Ph; i/f from IFc.
// -------------------------------------------------------------------------
__global__ __launch_bounds__(256) void d3_out(
    const _Float16* __restrict__ Ph, const float* __restrict__ IFc,
    const float* __restrict__ M,
    const float* __restrict__ CS, const float* __restrict__ NS,
    float* __restrict__ out) {
  int c = blockIdx.x >> 4, h = blockIdx.x & 15;
  int t0 = c << 6, hb = 32 + (h << 8);
  int tid = threadIdx.x;
  __shared__ float KP[64][65];   // K, later overwritten with P=W.*S
  __shared__ float Ql[64][65];
  __shared__ float Vl[64][65];
  __shared__ float Cst[64][65];
  __shared__ float cf[64], il[64], ml[64], dl[64], nq[64], den[64], nsl[64];
#pragma unroll
  for (int i = 0; i < 2; ++i) {
    int fq = (i << 8) + tid;              // 0..511
    int s = fq >> 3, b8 = (fq & 7) << 3;
    const _Float16* row = Ph + (size_t)(t0 + s) * NPAD + hb;
    f16x8 kv = *(const f16x8*)(row + b8);
    f16x8 qv = *(const f16x8*)(row + 64 + b8);
    f16x8 vv = *(const f16x8*)(row + 128 + b8);
#pragma unroll
    for (int j = 0; j < 8; ++j) {
      KP[s][b8 + j] = (float)kv[j];
      Ql[s][b8 + j] = (float)qv[j];
      Vl[s][b8 + j] = (float)vv[j];
    }
  }
#pragma unroll
  for (int i = 0; i < 4; ++i) {
    int fq = (i << 8) + tid;
    int s = fq >> 4, b4 = (fq & 15) << 2;
    float4 cv = *(const float4*)(CS + ((((size_t)(c << 4)) + h) << 12) + ((size_t)s << 6) + b4);
    Cst[s][b4 + 0] = cv.x; Cst[s][b4 + 1] = cv.y; Cst[s][b4 + 2] = cv.z; Cst[s][b4 + 3] = cv.w;
  }
  float iv = 0.f, mt = 0.f, cs = 0.f;
  if (tid < 64) {
    float2 iff = *(const float2*)(IFc + ((size_t)(t0 + tid) << 5) + (h << 1));
    iv = iff.x;
    float fv = iff.y;
    mt = M[(size_t)(t0 + tid) * NH + h];
    nsl[tid] = NS[((size_t)(c << 4) + h) * 64 + tid];
    cs = fv;
#pragma unroll
    for (int dd = 1; dd < 64; dd <<= 1) {
      float o = __shfl_up(cs, dd, 64);
      cs += (tid >= dd) ? o : 0.f;
    }
  }
  __syncthreads();
  if (tid < 64) {
    cf[tid] = cs; il[tid] = iv; ml[tid] = mt;
    float mstart = (c > 0) ? M[(size_t)(t0 - 1) * NH + h] : 0.f;
    dl[tid] = __expf(mstart + cs - mt);
    float acc = 0.f;
#pragma unroll
    for (int b = 0; b < 64; ++b) acc = fmaf(nsl[b], Ql[tid][b], acc);
    nq[tid] = acc;
  }
  __syncthreads();

  int tq = (tid >> 4) << 2;
  int aq = (tid & 15) << 2;
  float S[4][4];
#pragma unroll
  for (int i = 0; i < 4; ++i)
#pragma unroll
    for (int j = 0; j < 4; ++j) S[i][j] = 0.f;
  for (int b = 0; b < 64; ++b) {
    float qv[4], kv[4];
#pragma unroll
    for (int i = 0; i < 4; ++i) qv[i] = Ql[tq + i][b];
#pragma unroll
    for (int j = 0; j < 4; ++j) kv[j] = KP[aq + j][b];
#pragma unroll
    for (int i = 0; i < 4; ++i)
#pragma unroll
      for (int j = 0; j < 4; ++j) S[i][j] = fmaf(qv[i], kv[j], S[i][j]);
  }
  float ps[4] = {0.f, 0.f, 0.f, 0.f};
#pragma unroll
  for (int i = 0; i < 4; ++i) {
    int t = tq + i;
    float at = cf[t], mtt = ml[t];
#pragma unroll
    for (int j = 0; j < 4; ++j) {
      int s = aq + j;
      float w = (s <= t) ? __expf(at - cf[s] + il[s] - mtt) : 0.f;
      S[i][j] *= w;
      ps[i] += S[i][j];
    }
  }
#pragma unroll
  for (int i = 0; i < 4; ++i) {
    float p = ps[i];
    p += __shfl_xor(p, 1);
    p += __shfl_xor(p, 2);
    p += __shfl_xor(p, 4);
    p += __shfl_xor(p, 8);
    ps[i] = p;
  }
  if ((tid & 15) == 0) {
#pragma unroll
    for (int i = 0; i < 4; ++i) den[tq + i] = ps[i];
  }
  __syncthreads();
#pragma unroll
  for (int i = 0; i < 4; ++i)
#pragma unroll
    for (int j = 0; j < 4; ++j) KP[tq + i][aq + j] = S[i][j];
  __syncthreads();

  float Hh[4][4], inter[4][4];
#pragma unroll
  for (int i = 0; i < 4; ++i)
#pragma unroll
    for (int j = 0; j < 4; ++j) { Hh[i][j] = 0.f; inter[i][j] = 0.f; }
  for (int s = 0; s < 64; ++s) {
    float pv[4], vv[4];
#pragma unroll
    for (int i = 0; i < 4; ++i) pv[i] = KP[tq + i][s];
#pragma unroll
    for (int j = 0; j < 4; ++j) vv[j] = Vl[s][aq + j];
#pragma unroll
    for (int i = 0; i < 4; ++i)
#pragma unroll
      for (int j = 0; j < 4; ++j) Hh[i][j] = fmaf(pv[i], vv[j], Hh[i][j]);
  }
  for (int b = 0; b < 64; ++b) {
    float qv[4], cv[4];
#pragma unroll
    for (int i = 0; i < 4; ++i) qv[i] = Ql[tq + i][b];
#pragma unroll
    for (int j = 0; j < 4; ++j) cv[j] = Cst[aq + j][b];
#pragma unroll
    for (int i = 0; i < 4; ++i)
#pragma unroll
      for (int j = 0; j < 4; ++j) inter[i][j] = fmaf(qv[i], cv[j], inter[i][j]);
  }
#pragma unroll
  for (int i = 0; i < 4; ++i) {
    int t = tq + i;
    float dt = dl[t];
    float dn = fmaf(dt, nq[t], den[t]);
    float rinv = 1.f / fmaxf(fabsf(dn), 1.f);
    const _Float16* orow = Ph + (size_t)(t0 + t) * NPAD + hb + 192 + aq;
    f16x4 op4 = *(const f16x4*)orow;
    float o0 = 1.f / (1.f + __expf(-(float)op4[0]));
    float o1 = 1.f / (1.f + __expf(-(float)op4[1]));
    float o2 = 1.f / (1.f + __expf(-(float)op4[2]));
    float o3 = 1.f / (1.f + __expf(-(float)op4[3]));
    float4 st;
    st.x = o0 * (fmaf(dt, inter[i][0], Hh[i][0]) * rinv);
    st.y = o1 * (fmaf(dt, inter[i][1], Hh[i][1]) * rinv);
    st.z = o2 * (fmaf(dt, inter[i][2], Hh[i][2]) * rinv);
    st.w = o3 * (fmaf(dt, inter[i][3], Hh[i][3]) * rinv);
    *(float4*)(out + (size_t)(t0 + t) * 1024 + (h << 6) + aq) = st;
  }
}

// -------------------------------------------------------------------------
extern "C" void kernel_launch(void* const* d_in, const int* in_sizes, int n_in,
                              void* d_out, int out_size, void* d_ws, size_t ws_size,
                              hipStream_t stream) {
  const float* xs   = (const float*)d_in[0];
  const float* ifw  = (const float*)d_in[1];
  const float* ow   = (const float*)d_in[2];
  const float* kqw  = (const float*)d_in[3];
  const float* vw   = (const float*)d_in[4];
  const float* ifb  = (const float*)d_in[5];
  const float* ob   = (const float*)d_in[6];
  const float* kvqb = (const float*)d_in[7];
  float* ws   = (float*)d_ws;
  _Float16* Wph = (_Float16*)(ws + OFF_WP);
  float* BgDC = ws + OFF_BG;                         // [8][65536]
  float* BgDN = BgDC + (size_t)NGRP * 65536;         // [8][1024]
  float* Ag   = BgDN + (size_t)NGRP * 1024;          // [8][16]
  float* bias = ws + OFF_BIAS;
  _Float16* Phm = (_Float16*)(ws + OFF_P);
  float* Mm   = ws + OFF_M;
  float* DC   = ws + OFF_DC;
  _Float16* Xh = (_Float16*)(ws + OFF_DC);   // alias: consumed by gemm before d1 writes DC
  float* DN   = ws + OFF_DN;
  float* DL   = ws + OFF_DL;
  float* IFc  = ws + OFF_IF;
  float* outp = (float*)d_out;

  hipLaunchKernelGGL(pack_w, dim3((NPAD * D_IN) / 256), dim3(256), 0, stream,
                     ifw, ow, kqw, vw, ifb, ob, kvqb, Wph, bias);
  hipLaunchKernelGGL(conv_x, dim3((T_LEN * D_IN / 8) / 256), dim3(256), 0, stream, xs, Xh);
  hipLaunchKernelGGL(gemm_f16, dim3(33 * 64), dim3(256), 0, stream,
                     Xh, Wph, bias, Phm);
  hipLaunchKernelGGL(gemm_if, dim3(T_LEN / 64), dim3(256), 0, stream, xs, ifw, ifb, IFc);
  hipLaunchKernelGGL(mscan, dim3(NH), dim3(256), 0, stream, IFc, Mm);
  hipLaunchKernelGGL(d1_dc, dim3(NCH * NH), dim3(256), 0, stream, Phm, IFc, Mm, DC, DN, DL);
  hipLaunchKernelGGL(d2a, dim3(2080), dim3(256), 0, stream, DC, DN, DL, BgDC, BgDN, Ag);
  hipLaunchKernelGGL(d2c, dim3(2080), dim3(256), 0, stream, DC, DN, DL, BgDC, BgDN, Ag);
  hipLaunchKernelGGL(d3_out, dim3(NCH * NH), dim3(256), 0, stream, Phm, IFc, Mm, DC, DN, outp);
}

// Round 7
// 293.544 us; speedup vs baseline: 4.1242x; 1.0311x over previous
//
#include <hip/hip_runtime.h>
#include <math.h>

#define T_LEN 8192
#define D_IN  1024
#define NH    16
#define NPAD  4224   // 32 (i/f) + 16*256 (k,q,v,o per head), padded
#define NCH   128    // number of 64-step chunks
#define NGRP  8      // chunk groups for d2 scan
#define GSZ   16     // chunks per group
#define NPACK 16896  // pack_w blocks
#define NCONV 4096   // conv_x blocks

typedef __attribute__((ext_vector_type(8))) _Float16 f16x8;
typedef __attribute__((ext_vector_type(4))) _Float16 f16x4;
typedef __attribute__((ext_vector_type(4))) float f32x4;

// ---- workspace layout (float offsets) ----
static const size_t OFF_WP   = 0;                                  // Wph f16 [NPAD][1024] (2.16M floats)
static const size_t OFF_BG   = 2300000;                            // BgDC [8][65536] f32 + BgDN [8][1024] + Ag [8][16]
static const size_t OFF_BIAS = OFF_WP + (size_t)NPAD * D_IN;       // [NPAD] f32
static const size_t OFF_P    = OFF_BIAS + NPAD;                    // Ph f16 [T][NPAD]
static const size_t OFF_M    = OFF_P + (size_t)T_LEN * NPAD;       // [T][16] f32
static const size_t OFF_DC   = OFF_M + (size_t)T_LEN * NH;         // DCh f16 [NCH][16][64][64]; ALSO aliases Xh f16 (consumed first)
static const size_t OFF_DN   = OFF_DC + (size_t)NCH * NH * 64 * 64;// [NCH][16][64] f32
static const size_t OFF_DL   = OFF_DN + (size_t)NCH * NH * 64;     // [NCH][16] f32
static const size_t OFF_IF   = OFF_DL + (size_t)NCH * NH;          // IFc [T][32] f32

__device__ __forceinline__ void glds16(const void* g, void* l) {
  __builtin_amdgcn_global_load_lds(
      (const __attribute__((address_space(1))) void*)g,
      (__attribute__((address_space(3))) void*)l, 16, 0, 0);
}

// -------------------------------------------------------------------------
// Fused: pack weights (blocks [0,NPACK)) + X->f16 (blocks [NPACK,NPACK+NCONV))
// -------------------------------------------------------------------------
__global__ __launch_bounds__(256) void pack_conv(
    const float* __restrict__ ifw, const float* __restrict__ ow,
    const float* __restrict__ kqw, const float* __restrict__ vw,
    const float* __restrict__ ifb, const float* __restrict__ ob,
    const float* __restrict__ kvqb, _Float16* __restrict__ Wph,
    float* __restrict__ bias,
    const float* __restrict__ X, _Float16* __restrict__ Xh) {
  int b = blockIdx.x;
  if (b < NPACK) {
    int idx = b * 256 + threadIdx.x;
    int n = idx >> 10, d = idx & 1023;
    float w = 0.f, bb = 0.f;
    if (n < 32) {
      int h = n >> 1, t = n & 1;
      w = ifw[(h * 2 + t) * D_IN + d];
      bb = ifb[h * 2 + t];
    } else if (n < 4128) {
      int r = n - 32;
      int h = r >> 8, j = r & 255;
      if (j < 64)       { w = kqw[(h * 128 + j) * D_IN + d] * 0.125f; bb = kvqb[(h * 3 + 0) * 64 + j]; }
      else if (j < 128) { w = kqw[(h * 128 + j) * D_IN + d];          bb = kvqb[(h * 3 + 2) * 64 + (j - 64)]; }
      else if (j < 192) { w = vw[(h * 64 + (j - 128)) * D_IN + d];    bb = kvqb[(h * 3 + 1) * 64 + (j - 128)]; }
      else              { w = ow[(h * 64 + (j - 192)) * D_IN + d];    bb = ob[h * 64 + (j - 192)]; }
    }
    Wph[(size_t)n * D_IN + d] = (_Float16)w;
    if (d == 0) bias[n] = bb;
  } else {
    int i = ((b - NPACK) * 256 + threadIdx.x) << 3;
    float4 v0 = *(const float4*)(X + i);
    float4 v1 = *(const float4*)(X + i + 4);
    f16x8 r;
    r[0] = (_Float16)v0.x; r[1] = (_Float16)v0.y; r[2] = (_Float16)v0.z; r[3] = (_Float16)v0.w;
    r[4] = (_Float16)v1.x; r[5] = (_Float16)v1.y; r[6] = (_Float16)v1.z; r[7] = (_Float16)v1.w;
    *(f16x8*)(Xh + i) = r;
  }
}

// -------------------------------------------------------------------------
// f16 MFMA GEMM: Ph = Xh * Wph^T + bias.  m97 fragment structure +
// XCD-chunked swizzle + 2-phase LDS double-buffer (stage t+1 before
// compute t; ONE barrier per K-step — T3-minimum recipe).
// -------------------------------------------------------------------------
__global__ __launch_bounds__(256) void gemm_f16(
    const _Float16* __restrict__ Xh, const _Float16* __restrict__ Wph,
    const float* __restrict__ bias, _Float16* __restrict__ Ph) {
  __shared__ _Float16 As[2][128 * 32];
  __shared__ _Float16 Bs[2][128 * 32];
  int tid = threadIdx.x;
  int wave = tid >> 6, lane = tid & 63;
  int wgid = blockIdx.x;
  int virt = (wgid & 7) * 264 + (wgid >> 3);
  int mt = virt / 33, nt = virt % 33;
  int m0 = mt << 7, n0 = nt << 7;
  int wr = wave >> 1, wc = wave & 1;

  f32x4 acc[4][4];
  f32x4 zero = {0.f, 0.f, 0.f, 0.f};
#pragma unroll
  for (int i = 0; i < 4; ++i)
#pragma unroll
    for (int j = 0; j < 4; ++j) acc[i][j] = zero;

  int srow = lane >> 2;
  int scol = (lane & 3) << 3;
  const _Float16* ga = Xh + (size_t)(m0 + wave * 32 + srow) * D_IN + scol;
  const _Float16* gb = Wph + (size_t)(n0 + wave * 32 + srow) * D_IN + scol;
  int lds0 = (wave * 32) * 32;
  int lds1 = (wave * 32 + 16) * 32;

  int fr = lane & 15;
  int fk = (lane >> 4) << 3;

  // prologue: stage tile 0 into buf 0
  glds16(ga, &As[0][lds0]);
  glds16(ga + 16 * D_IN, &As[0][lds1]);
  glds16(gb, &Bs[0][lds0]);
  glds16(gb + 16 * D_IN, &Bs[0][lds1]);
  __syncthreads();                    // drains vmcnt(0): tile 0 staged

  int cur = 0;
  for (int k0 = 0; k0 < D_IN; k0 += 32) {
    if (k0 + 32 < D_IN) {             // issue next tile into other buffer
      int kn = k0 + 32;
      glds16(ga + kn, &As[cur ^ 1][lds0]);
      glds16(ga + 16 * D_IN + kn, &As[cur ^ 1][lds1]);
      glds16(gb + kn, &Bs[cur ^ 1][lds0]);
      glds16(gb + 16 * D_IN + kn, &Bs[cur ^ 1][lds1]);
    }
    f16x8 a[4], b[4];
#pragma unroll
    for (int mi = 0; mi < 4; ++mi)
      a[mi] = *(const f16x8*)&As[cur][(wr * 64 + mi * 16 + fr) * 32 + fk];
#pragma unroll
    for (int ni = 0; ni < 4; ++ni)
      b[ni] = *(const f16x8*)&Bs[cur][(wc * 64 + ni * 16 + fr) * 32 + fk];
#pragma unroll
    for (int mi = 0; mi < 4; ++mi)
#pragma unroll
      for (int ni = 0; ni < 4; ++ni)
        acc[mi][ni] = __builtin_amdgcn_mfma_f32_16x16x32_f16(a[mi], b[ni], acc[mi][ni], 0, 0, 0);
    __syncthreads();                  // drains next-tile loads; all reads of cur done
    cur ^= 1;
  }

  int cr = (lane >> 4) << 2;
  int cc = lane & 15;
#pragma unroll
  for (int mi = 0; mi < 4; ++mi) {
#pragma unroll
    for (int ni = 0; ni < 4; ++ni) {
      int col = n0 + wc * 64 + ni * 16 + cc;
      float bb = bias[col];
      size_t base = (size_t)(m0 + wr * 64 + mi * 16 + cr) * NPAD + col;
#pragma unroll
      for (int r = 0; r < 4; ++r)
        Ph[base + (size_t)r * NPAD] = (_Float16)(acc[mi][ni][r] + bb);
    }
  }
}

// -------------------------------------------------------------------------
// fp32 exact i/f columns, LDS-tiled -> IFc[T][32] only.
// -------------------------------------------------------------------------
__global__ __launch_bounds__(256) void gemm_if(
    const float* __restrict__ X, const float* __restrict__ ifw,
    const float* __restrict__ ifb, float* __restrict__ IFc) {
  __shared__ float Xs[64 * 72];
  __shared__ float Ws[32 * 68];
  int tid = threadIdx.x;
  int r0 = blockIdx.x << 6;
  int nc = tid & 15;
  int rg = tid >> 4;
  int n0 = nc << 1;
  int sw = ((n0 >> 3) & 3) << 2;
  int sx = (rg & 3) << 2;

  float acc[4][2];
#pragma unroll
  for (int j = 0; j < 4; ++j) { acc[j][0] = 0.f; acc[j][1] = 0.f; }

  for (int k0 = 0; k0 < D_IN; k0 += 64) {
    __syncthreads();
#pragma unroll
    for (int i = 0; i < 4; ++i) {
      int fi = (i << 8) + tid;
      int row = fi >> 4, kk = (fi & 15) << 2;
      float4 v = *(const float4*)(X + (size_t)(r0 + row) * D_IN + k0 + kk);
      *(float4*)&Xs[row * 72 + (kk ^ (((row >> 2) & 3) << 2))] = v;
    }
#pragma unroll
    for (int i = 0; i < 2; ++i) {
      int fi = (i << 8) + tid;
      int row = fi >> 4, kk = (fi & 15) << 2;
      float4 v = *(const float4*)(ifw + (size_t)row * D_IN + k0 + kk);
      *(float4*)&Ws[row * 68 + (kk ^ (((row >> 3) & 3) << 2))] = v;
    }
    __syncthreads();
#pragma unroll
    for (int k4 = 0; k4 < 64; k4 += 4) {
      float4 w0 = *(const float4*)&Ws[n0 * 68 + (k4 ^ sw)];
      float4 w1 = *(const float4*)&Ws[(n0 + 1) * 68 + (k4 ^ sw)];
#pragma unroll
      for (int j = 0; j < 4; ++j) {
        float4 xv = *(const float4*)&Xs[((rg << 2) + j) * 72 + (k4 ^ sx)];
        acc[j][0] = fmaf(xv.x, w0.x, acc[j][0]);
        acc[j][0] = fmaf(xv.y, w0.y, acc[j][0]);
        acc[j][0] = fmaf(xv.z, w0.z, acc[j][0]);
        acc[j][0] = fmaf(xv.w, w0.w, acc[j][0]);
        acc[j][1] = fmaf(xv.x, w1.x, acc[j][1]);
        acc[j][1] = fmaf(xv.y, w1.y, acc[j][1]);
        acc[j][1] = fmaf(xv.z, w1.z, acc[j][1]);
        acc[j][1] = fmaf(xv.w, w1.w, acc[j][1]);
      }
    }
  }
  float b0 = ifb[n0], b1 = ifb[n0 + 1];
#pragma unroll
  for (int j = 0; j < 4; ++j) {
    int row = r0 + (rg << 2) + j;
    float2 st; st.x = acc[j][0] + b0; st.y = acc[j][1] + b1;
    *(float2*)(IFc + ((size_t)row << 5) + n0) = st;
  }
}

// -------------------------------------------------------------------------
// Parallel m-scan (associative (max,+) compose), 16 blocks x 256 threads.
// -------------------------------------------------------------------------
__global__ __launch_bounds__(256) void mscan(const float* __restrict__ IFc, float* __restrict__ M) {
  int h = blockIdx.x;
  int tid = threadIdx.x;
  int lane = tid & 63, wv = tid >> 6;
  int t0 = tid << 5;
  float F = 0.f, I = -1e30f;
#pragma unroll 8
  for (int u = 0; u < 32; ++u) {
    float2 v = *(const float2*)(IFc + ((size_t)(t0 + u) << 5) + (h << 1));
    I = fmaxf(I + v.y, v.x);
    F += v.y;
  }
#pragma unroll
  for (int d = 1; d < 64; d <<= 1) {
    float Fo = __shfl_up(F, d, 64);
    float Io = __shfl_up(I, d, 64);
    if (lane >= d) { I = fmaxf(Io + F, I); F = Fo + F; }
  }
  __shared__ float sF[4], sI[4];
  if (lane == 63) { sF[wv] = F; sI[wv] = I; }
  float Fe = __shfl_up(F, 1, 64);
  float Ie = __shfl_up(I, 1, 64);
  if (lane == 0) { Fe = 0.f; Ie = -1e30f; }
  __syncthreads();
  float Fp = 0.f, Ip = -1e30f;
  for (int w = 0; w < wv; ++w) { Ip = fmaxf(Ip + sF[w], sI[w]); Fp += sF[w]; }
  float Ft = Fp + Fe;
  float It = fmaxf(Ip + Fe, Ie);
  float m = fmaxf(Ft, It);
#pragma unroll 8
  for (int u = 0; u < 32; ++u) {
    float2 v = *(const float2*)(IFc + ((size_t)(t0 + u) << 5) + (h << 1));
    m = fmaxf(v.y + m, v.x);
    M[(size_t)(t0 + u) * NH + h] = m;
  }
}

// -------------------------------------------------------------------------
// D1: DC(f16) = sum_s g_s v_s k_s^T, DN = sum_s g_s k_s, DL.
// -------------------------------------------------------------------------
__global__ __launch_bounds__(256) void d1_dc(
    const _Float16* __restrict__ Ph, const float* __restrict__ IFc,
    const float* __restrict__ M,
    _Float16* __restrict__ DCh, float* __restrict__ DN, float* __restrict__ DL) {
  int c = blockIdx.x >> 4, h = blockIdx.x & 15;
  int t0 = c << 6, hb = 32 + (h << 8);
  int tid = threadIdx.x;
  __shared__ float Kl[64][65];
  __shared__ float Vl[64][65];
  __shared__ float gl[64];
#pragma unroll
  for (int i = 0; i < 2; ++i) {
    int fq = (i << 8) + tid;
    int s = fq >> 3, b8 = (fq & 7) << 3;
    const _Float16* row = Ph + (size_t)(t0 + s) * NPAD + hb;
    f16x8 kv = *(const f16x8*)(row + b8);
    f16x8 vv = *(const f16x8*)(row + 128 + b8);
#pragma unroll
    for (int j = 0; j < 8; ++j) {
      Kl[s][b8 + j] = (float)kv[j];
      Vl[s][b8 + j] = (float)vv[j];
    }
  }
  if (tid < 64) {
    float2 iff = *(const float2*)(IFc + ((size_t)(t0 + tid) << 5) + (h << 1));
    float iv = iff.x, fv = iff.y;
    float cs = fv;
#pragma unroll
    for (int dd = 1; dd < 64; dd <<= 1) {
      float o = __shfl_up(cs, dd, 64);
      cs += (tid >= dd) ? o : 0.f;
    }
    float cumL = __shfl(cs, 63, 64);
    float mL = M[(size_t)(t0 + 63) * NH + h];
    gl[tid] = __expf(cumL - cs + iv - mL);
    if (tid == 0) {
      float mstart = (c > 0) ? M[(size_t)(t0 - 1) * NH + h] : 0.f;
      DL[(c << 4) + h] = __expf(mstart + cumL - mL);
    }
  }
  __syncthreads();
  if (tid < 64) {
    float acc = 0.f;
#pragma unroll
    for (int s = 0; s < 64; ++s) acc = fmaf(gl[s], Kl[s][tid], acc);
    DN[((size_t)(c << 4) + h) * 64 + tid] = acc;
  }
  int a = tid & 63, bq = tid >> 6;
  float acc[16];
#pragma unroll
  for (int j = 0; j < 16; ++j) acc[j] = 0.f;
  for (int s = 0; s < 64; ++s) {
    float gv = gl[s] * Vl[s][a];
#pragma unroll
    for (int j = 0; j < 16; ++j) acc[j] = fmaf(gv, Kl[s][(bq << 4) + j], acc[j]);
  }
  size_t base = (((size_t)(c << 4) + h) << 12) + ((size_t)a << 6) + (bq << 4);
  f16x8 s0, s1;
#pragma unroll
  for (int j = 0; j < 8; ++j) { s0[j] = (_Float16)acc[j]; s1[j] = (_Float16)acc[8 + j]; }
  *(f16x8*)(DCh + base) = s0;
  *(f16x8*)(DCh + base + 8) = s1;
}

// -------------------------------------------------------------------------
// D2a: per (group, elem) affine aggregates over the group's 16 chunks.
// -------------------------------------------------------------------------
__global__ __launch_bounds__(256) void d2a(
    const _Float16* __restrict__ DCh, const float* __restrict__ DN,
    const float* __restrict__ DL,
    float* __restrict__ BgDC, float* __restrict__ BgDN, float* __restrict__ Ag) {
  int bid = blockIdx.x, tid = threadIdx.x;
  if (bid < 2048) {
    int linear = (bid << 8) + tid;
    int g = linear >> 16, e = linear & 65535;
    int h = e >> 12;
    float carry = 0.f, a = 1.f;
    size_t idx = (size_t)e + ((size_t)g << 4) * 65536;
    float v = (float)DCh[idx];
    for (int u = 0; u < GSZ; ++u) {
      float dl = DL[(((g << 4) + u) << 4) + h];
      float vn = (u < GSZ - 1) ? (float)DCh[idx + 65536] : 0.f;
      carry = fmaf(dl, carry, v);
      a *= dl;
      v = vn;
      idx += 65536;
    }
    BgDC[((size_t)g << 16) + e] = carry;
    if ((e & 4095) == 0) Ag[(g << 4) + h] = a;
  } else {
    int linear = ((bid - 2048) << 8) + tid;
    int g = linear >> 10, e = linear & 1023;
    int h = e >> 6;
    float carry = 0.f;
    size_t idx = (size_t)e + ((size_t)g << 4) * 1024;
    float v = DN[idx];
    for (int u = 0; u < GSZ; ++u) {
      float dl = DL[(((g << 4) + u) << 4) + h];
      float vn = (u < GSZ - 1) ? DN[idx + 1024] : 0.f;
      carry = fmaf(dl, carry, v);
      v = vn;
      idx += 1024;
    }
    BgDN[(g << 10) + e] = carry;
  }
}

// -------------------------------------------------------------------------
// D2c: inline exclusive group-prefix then in-place exclusive carries.
// -------------------------------------------------------------------------
__global__ __launch_bounds__(256) void d2c(
    _Float16* __restrict__ DCh, float* __restrict__ DN,
    const float* __restrict__ DL,
    const float* __restrict__ BgDC, const float* __restrict__ BgDN,
    const float* __restrict__ Ag) {
  int bid = blockIdx.x, tid = threadIdx.x;
  if (bid < 2048) {
    int linear = (bid << 8) + tid;
    int g = linear >> 16, e = linear & 65535;
    int h = e >> 12;
    float P = 0.f;
    for (int gp = 0; gp < g; ++gp)
      P = fmaf(Ag[(gp << 4) + h], P, BgDC[((size_t)gp << 16) + e]);
    float carry = P;
    size_t idx = (size_t)e + ((size_t)g << 4) * 65536;
    float v = (float)DCh[idx];
    for (int u = 0; u < GSZ; ++u) {
      float dl = DL[(((g << 4) + u) << 4) + h];
      float vn = (u < GSZ - 1) ? (float)DCh[idx + 65536] : 0.f;
      DCh[idx] = (_Float16)carry;
      carry = fmaf(dl, carry, v);
      v = vn;
      idx += 65536;
    }
  } else {
    int linear = ((bid - 2048) << 8) + tid;
    int g = linear >> 10, e = linear & 1023;
    int h = e >> 6;
    float P = 0.f;
    for (int gp = 0; gp < g; ++gp)
      P = fmaf(Ag[(gp << 4) + h], P, BgDN[(gp << 10) + e]);
    float carry = P;
    size_t idx = (size_t)e + ((size_t)g << 4) * 1024;
    float v = DN[idx];
    for (int u = 0; u < GSZ; ++u) {
      float dl = DL[(((g << 4) + u) << 4) + h];
      float vn = (u < GSZ - 1) ? DN[idx + 1024] : 0.f;
      DN[idx] = carry;
      carry = fmaf(dl, carry, v);
      v = vn;
      idx += 1024;
    }
  }
}

// -------------------------------------------------------------------------
// D3: per (chunk,head) outputs. K/Q/V/O from f16 Ph; Cstart from f16 DCh.
// -------------------------------------------------------------------------
__global__ __launch_bounds__(256) void d3_out(
    const _Float16* __restrict__ Ph, const float* __restrict__ IFc,
    const float* __restrict__ M,
    const _Float16* __restrict__ CS, const float* __restrict__ NS,
    float* __restrict__ out) {
  int c = blockIdx.x >> 4, h = blockIdx.x & 15;
  int t0 = c << 6, hb = 32 + (h << 8);
  int tid = threadIdx.x;
  __shared__ float KP[64][65];   // K, later overwritten with P=W.*S
  __shared__ float Ql[64][65];
  __shared__ float Vl[64][65];
  __shared__ float Cst[64][65];
  __shared__ float cf[64], il[64], ml[64], dl[64], nq[64], den[64], nsl[64];
#pragma unroll
  for (int i = 0; i < 2; ++i) {
    int fq = (i << 8) + tid;
    int s = fq >> 3, b8 = (fq & 7) << 3;
    const _Float16* row = Ph + (size_t)(t0 + s) * NPAD + hb;
    f16x8 kv = *(const f16x8*)(row + b8);
    f16x8 qv = *(const f16x8*)(row + 64 + b8);
    f16x8 vv = *(const f16x8*)(row + 128 + b8);
    f16x8 cv = *(const f16x8*)(CS + ((((size_t)(c << 4)) + h) << 12) + ((size_t)s << 6) + b8);
#pragma unroll
    for (int j = 0; j < 8; ++j) {
      KP[s][b8 + j] = (float)kv[j];
      Ql[s][b8 + j] = (float)qv[j];
      Vl[s][b8 + j] = (float)vv[j];
      Cst[s][b8 + j] = (float)cv[j];
    }
  }
  float iv = 0.f, mt = 0.f, cs = 0.f;
  if (tid < 64) {
    float2 iff = *(const float2*)(IFc + ((size_t)(t0 + tid) << 5) + (h << 1));
    iv = iff.x;
    float fv = iff.y;
    mt = M[(size_t)(t0 + tid) * NH + h];
    nsl[tid] = NS[((size_t)(c << 4) + h) * 64 + tid];
    cs = fv;
#pragma unroll
    for (int dd = 1; dd < 64; dd <<= 1) {
      float o = __shfl_up(cs, dd, 64);
      cs += (tid >= dd) ? o : 0.f;
    }
  }
  __syncthreads();
  if (tid < 64) {
    cf[tid] = cs; il[tid] = iv; ml[tid] = mt;
    float mstart = (c > 0) ? M[(size_t)(t0 - 1) * NH + h] : 0.f;
    dl[tid] = __expf(mstart + cs - mt);
    float acc = 0.f;
#pragma unroll
    for (int b = 0; b < 64; ++b) acc = fmaf(nsl[b], Ql[tid][b], acc);
    nq[tid] = acc;
  }
  __syncthreads();

  int tq = (tid >> 4) << 2;
  int aq = (tid & 15) << 2;
  float S[4][4];
#pragma unroll
  for (int i = 0; i < 4; ++i)
#pragma unroll
    for (int j = 0; j < 4; ++j) S[i][j] = 0.f;
  for (int b = 0; b < 64; ++b) {
    float qv[4], kv[4];
#pragma unroll
    for (int i = 0; i < 4; ++i) qv[i] = Ql[tq + i][b];
#pragma unroll
    for (int j = 0; j < 4; ++j) kv[j] = KP[aq + j][b];
#pragma unroll
    for (int i = 0; i < 4; ++i)
#pragma unroll
      for (int j = 0; j < 4; ++j) S[i][j] = fmaf(qv[i], kv[j], S[i][j]);
  }
  float ps[4] = {0.f, 0.f, 0.f, 0.f};
#pragma unroll
  for (int i = 0; i < 4; ++i) {
    int t = tq + i;
    float at = cf[t], mtt = ml[t];
#pragma unroll
    for (int j = 0; j < 4; ++j) {
      int s = aq + j;
      float w = (s <= t) ? __expf(at - cf[s] + il[s] - mtt) : 0.f;
      S[i][j] *= w;
      ps[i] += S[i][j];
    }
  }
#pragma unroll
  for (int i = 0; i < 4; ++i) {
    float p = ps[i];
    p += __shfl_xor(p, 1);
    p += __shfl_xor(p, 2);
    p += __shfl_xor(p, 4);
    p += __shfl_xor(p, 8);
    ps[i] = p;
  }
  if ((tid & 15) == 0) {
#pragma unroll
    for (int i = 0; i < 4; ++i) den[tq + i] = ps[i];
  }
  __syncthreads();
#pragma unroll
  for (int i = 0; i < 4; ++i)
#pragma unroll
    for (int j = 0; j < 4; ++j) KP[tq + i][aq + j] = S[i][j];
  __syncthreads();

  float Hh[4][4], inter[4][4];
#pragma unroll
  for (int i = 0; i < 4; ++i)
#pragma unroll
    for (int j = 0; j < 4; ++j) { Hh[i][j] = 0.f; inter[i][j] = 0.f; }
  for (int s = 0; s < 64; ++s) {
    float pv[4], vv[4];
#pragma unroll
    for (int i = 0; i < 4; ++i) pv[i] = KP[tq + i][s];
#pragma unroll
    for (int j = 0; j < 4; ++j) vv[j] = Vl[s][aq + j];
#pragma unroll
    for (int i = 0; i < 4; ++i)
#pragma unroll
      for (int j = 0; j < 4; ++j) Hh[i][j] = fmaf(pv[i], vv[j], Hh[i][j]);
  }
  for (int b = 0; b < 64; ++b) {
    float qv[4], cv[4];
#pragma unroll
    for (int i = 0; i < 4; ++i) qv[i] = Ql[tq + i][b];
#pragma unroll
    for (int j = 0; j < 4; ++j) cv[j] = Cst[aq + j][b];
#pragma unroll
    for (int i = 0; i < 4; ++i)
#pragma unroll
      for (int j = 0; j < 4; ++j) inter[i][j] = fmaf(qv[i], cv[j], inter[i][j]);
  }
#pragma unroll
  for (int i = 0; i < 4; ++i) {
    int t = tq + i;
    float dt = dl[t];
    float dn = fmaf(dt, nq[t], den[t]);
    float rinv = 1.f / fmaxf(fabsf(dn), 1.f);
    const _Float16* orow = Ph + (size_t)(t0 + t) * NPAD + hb + 192 + aq;
    f16x4 op4 = *(const f16x4*)orow;
    float o0 = 1.f / (1.f + __expf(-(float)op4[0]));
    float o1 = 1.f / (1.f + __expf(-(float)op4[1]));
    float o2 = 1.f / (1.f + __expf(-(float)op4[2]));
    float o3 = 1.f / (1.f + __expf(-(float)op4[3]));
    float4 st;
    st.x = o0 * (fmaf(dt, inter[i][0], Hh[i][0]) * rinv);
    st.y = o1 * (fmaf(dt, inter[i][1], Hh[i][1]) * rinv);
    st.z = o2 * (fmaf(dt, inter[i][2], Hh[i][2]) * rinv);
    st.w = o3 * (fmaf(dt, inter[i][3], Hh[i][3]) * rinv);
    *(float4*)(out + (size_t)(t0 + t) * 1024 + (h << 6) + aq) = st;
  }
}

// -------------------------------------------------------------------------
extern "C" void kernel_launch(void* const* d_in, const int* in_sizes, int n_in,
                              void* d_out, int out_size, void* d_ws, size_t ws_size,
                              hipStream_t stream) {
  const float* xs   = (const float*)d_in[0];
  const float* ifw  = (const float*)d_in[1];
  const float* ow   = (const float*)d_in[2];
  const float* kqw  = (const float*)d_in[3];
  const float* vw   = (const float*)d_in[4];
  const float* ifb  = (const float*)d_in[5];
  const float* ob   = (const float*)d_in[6];
  const float* kvqb = (const float*)d_in[7];
  float* ws   = (float*)d_ws;
  _Float16* Wph = (_Float16*)(ws + OFF_WP);
  float* BgDC = ws + OFF_BG;
  float* BgDN = BgDC + (size_t)NGRP * 65536;
  float* Ag   = BgDN + (size_t)NGRP * 1024;
  float* bias = ws + OFF_BIAS;
  _Float16* Phm = (_Float16*)(ws + OFF_P);
  float* Mm   = ws + OFF_M;
  _Float16* DCh = (_Float16*)(ws + OFF_DC);
  _Float16* Xh  = (_Float16*)(ws + OFF_DC);  // alias: consumed by gemm before d1 writes DCh
  float* DN   = ws + OFF_DN;
  float* DL   = ws + OFF_DL;
  float* IFc  = ws + OFF_IF;
  float* outp = (float*)d_out;

  hipLaunchKernelGGL(pack_conv, dim3(NPACK + NCONV), dim3(256), 0, stream,
                     ifw, ow, kqw, vw, ifb, ob, kvqb, Wph, bias, xs, Xh);
  hipLaunchKernelGGL(gemm_f16, dim3(33 * 64), dim3(256), 0, stream,
                     Xh, Wph, bias, Phm);
  hipLaunchKernelGGL(gemm_if, dim3(T_LEN / 64), dim3(256), 0, stream, xs, ifw, ifb, IFc);
  hipLaunchKernelGGL(mscan, dim3(NH), dim3(256), 0, stream, IFc, Mm);
  hipLaunchKernelGGL(d1_dc, dim3(NCH * NH), dim3(256), 0, stream, Phm, IFc, Mm, DCh, DN, DL);
  hipLaunchKernelGGL(d2a, dim3(2080), dim3(256), 0, stream, DCh, DN, DL, BgDC, BgDN, Ag);
  hipLaunchKernelGGL(d2c, dim3(2080), dim3(256), 0, stream, DCh, DN, DL, BgDC, BgDN, Ag);
  hipLaunchKernelGGL(d3_out, dim3(NCH * NH), dim3(256), 0, stream, Phm, IFc, Mm, DCh, DN, outp);
}

// Round 8
// 244.730 us; speedup vs baseline: 4.9468x; 1.1995x over previous
//
#include <hip/hip_runtime.h>
#include <math.h>

#define T_LEN 8192
#define D_IN  1024
#define NH    16
#define NPAD  4224   // 32 (i/f) + 16*256 (k,q,v,o per head), padded
#define NCH   128    // number of 64-step chunks
#define NGRP  8      // chunk groups for d2 scan
#define GSZ   16     // chunks per group
#define NPACK 16896  // pack_w blocks
#define NCONV 4096   // conv_x blocks

typedef __attribute__((ext_vector_type(8))) _Float16 f16x8;
typedef __attribute__((ext_vector_type(4))) _Float16 f16x4;
typedef __attribute__((ext_vector_type(4))) float f32x4;

// ---- workspace layout (float offsets) ----
static const size_t OFF_WP   = 0;                                  // Wph f16 [NPAD][1024] (2.16M floats)
static const size_t OFF_BG   = 2300000;                            // BgDC [8][65536] f32 + BgDN [8][1024] + Ag [8][16]
static const size_t OFF_BIAS = OFF_WP + (size_t)NPAD * D_IN;       // [NPAD] f32
static const size_t OFF_P    = OFF_BIAS + NPAD;                    // Ph f16 [T][NPAD]
static const size_t OFF_M    = OFF_P + (size_t)T_LEN * NPAD;       // [T][16] f32
static const size_t OFF_DC   = OFF_M + (size_t)T_LEN * NH;         // DCh f16 [NCH][16][64][64]; ALSO aliases Xh f16 (consumed first)
static const size_t OFF_DN   = OFF_DC + (size_t)NCH * NH * 64 * 64;// [NCH][16][64] f32
static const size_t OFF_DL   = OFF_DN + (size_t)NCH * NH * 64;     // [NCH][16] f32
static const size_t OFF_IF   = OFF_DL + (size_t)NCH * NH;          // IFc [T][32] f32

__device__ __forceinline__ void glds16(const void* g, void* l) {
  __builtin_amdgcn_global_load_lds(
      (const __attribute__((address_space(1))) void*)g,
      (__attribute__((address_space(3))) void*)l, 16, 0, 0);
}

// -------------------------------------------------------------------------
// Fused: pack weights (blocks [0,NPACK)) + X->f16 (blocks [NPACK,NPACK+NCONV))
// -------------------------------------------------------------------------
__global__ __launch_bounds__(256) void pack_conv(
    const float* __restrict__ ifw, const float* __restrict__ ow,
    const float* __restrict__ kqw, const float* __restrict__ vw,
    const float* __restrict__ ifb, const float* __restrict__ ob,
    const float* __restrict__ kvqb, _Float16* __restrict__ Wph,
    float* __restrict__ bias,
    const float* __restrict__ X, _Float16* __restrict__ Xh) {
  int b = blockIdx.x;
  if (b < NPACK) {
    int idx = b * 256 + threadIdx.x;
    int n = idx >> 10, d = idx & 1023;
    float w = 0.f, bb = 0.f;
    if (n < 32) {
      int h = n >> 1, t = n & 1;
      w = ifw[(h * 2 + t) * D_IN + d];
      bb = ifb[h * 2 + t];
    } else if (n < 4128) {
      int r = n - 32;
      int h = r >> 8, j = r & 255;
      if (j < 64)       { w = kqw[(h * 128 + j) * D_IN + d] * 0.125f; bb = kvqb[(h * 3 + 0) * 64 + j]; }
      else if (j < 128) { w = kqw[(h * 128 + j) * D_IN + d];          bb = kvqb[(h * 3 + 2) * 64 + (j - 64)]; }
      else if (j < 192) { w = vw[(h * 64 + (j - 128)) * D_IN + d];    bb = kvqb[(h * 3 + 1) * 64 + (j - 128)]; }
      else              { w = ow[(h * 64 + (j - 192)) * D_IN + d];    bb = ob[h * 64 + (j - 192)]; }
    }
    Wph[(size_t)n * D_IN + d] = (_Float16)w;
    if (d == 0) bias[n] = bb;
  } else {
    int i = ((b - NPACK) * 256 + threadIdx.x) << 3;
    float4 v0 = *(const float4*)(X + i);
    float4 v1 = *(const float4*)(X + i + 4);
    f16x8 r;
    r[0] = (_Float16)v0.x; r[1] = (_Float16)v0.y; r[2] = (_Float16)v0.z; r[3] = (_Float16)v0.w;
    r[4] = (_Float16)v1.x; r[5] = (_Float16)v1.y; r[6] = (_Float16)v1.z; r[7] = (_Float16)v1.w;
    *(f16x8*)(Xh + i) = r;
  }
}

// -------------------------------------------------------------------------
// f16 MFMA GEMM: Ph = Xh * Wph^T + bias.  m97 fragment structure +
// XCD-chunked swizzle + 2-phase LDS double-buffer.
// -------------------------------------------------------------------------
__global__ __launch_bounds__(256) void gemm_f16(
    const _Float16* __restrict__ Xh, const _Float16* __restrict__ Wph,
    const float* __restrict__ bias, _Float16* __restrict__ Ph) {
  __shared__ _Float16 As[2][128 * 32];
  __shared__ _Float16 Bs[2][128 * 32];
  int tid = threadIdx.x;
  int wave = tid >> 6, lane = tid & 63;
  int wgid = blockIdx.x;
  int virt = (wgid & 7) * 264 + (wgid >> 3);
  int mt = virt / 33, nt = virt % 33;
  int m0 = mt << 7, n0 = nt << 7;
  int wr = wave >> 1, wc = wave & 1;

  f32x4 acc[4][4];
  f32x4 zero = {0.f, 0.f, 0.f, 0.f};
#pragma unroll
  for (int i = 0; i < 4; ++i)
#pragma unroll
    for (int j = 0; j < 4; ++j) acc[i][j] = zero;

  int srow = lane >> 2;
  int scol = (lane & 3) << 3;
  const _Float16* ga = Xh + (size_t)(m0 + wave * 32 + srow) * D_IN + scol;
  const _Float16* gb = Wph + (size_t)(n0 + wave * 32 + srow) * D_IN + scol;
  int lds0 = (wave * 32) * 32;
  int lds1 = (wave * 32 + 16) * 32;

  int fr = lane & 15;
  int fk = (lane >> 4) << 3;

  glds16(ga, &As[0][lds0]);
  glds16(ga + 16 * D_IN, &As[0][lds1]);
  glds16(gb, &Bs[0][lds0]);
  glds16(gb + 16 * D_IN, &Bs[0][lds1]);
  __syncthreads();

  int cur = 0;
  for (int k0 = 0; k0 < D_IN; k0 += 32) {
    if (k0 + 32 < D_IN) {
      int kn = k0 + 32;
      glds16(ga + kn, &As[cur ^ 1][lds0]);
      glds16(ga + 16 * D_IN + kn, &As[cur ^ 1][lds1]);
      glds16(gb + kn, &Bs[cur ^ 1][lds0]);
      glds16(gb + 16 * D_IN + kn, &Bs[cur ^ 1][lds1]);
    }
    f16x8 a[4], b[4];
#pragma unroll
    for (int mi = 0; mi < 4; ++mi)
      a[mi] = *(const f16x8*)&As[cur][(wr * 64 + mi * 16 + fr) * 32 + fk];
#pragma unroll
    for (int ni = 0; ni < 4; ++ni)
      b[ni] = *(const f16x8*)&Bs[cur][(wc * 64 + ni * 16 + fr) * 32 + fk];
#pragma unroll
    for (int mi = 0; mi < 4; ++mi)
#pragma unroll
      for (int ni = 0; ni < 4; ++ni)
        acc[mi][ni] = __builtin_amdgcn_mfma_f32_16x16x32_f16(a[mi], b[ni], acc[mi][ni], 0, 0, 0);
    __syncthreads();
    cur ^= 1;
  }

  int cr = (lane >> 4) << 2;
  int cc = lane & 15;
#pragma unroll
  for (int mi = 0; mi < 4; ++mi) {
#pragma unroll
    for (int ni = 0; ni < 4; ++ni) {
      int col = n0 + wc * 64 + ni * 16 + cc;
      float bb = bias[col];
      size_t base = (size_t)(m0 + wr * 64 + mi * 16 + cr) * NPAD + col;
#pragma unroll
      for (int r = 0; r < 4; ++r)
        Ph[base + (size_t)r * NPAD] = (_Float16)(acc[mi][ni][r] + bb);
    }
  }
}

// -------------------------------------------------------------------------
// fp32 exact i/f columns, LDS-tiled -> IFc[T][32] only.
// -------------------------------------------------------------------------
__global__ __launch_bounds__(256) void gemm_if(
    const float* __restrict__ X, const float* __restrict__ ifw,
    const float* __restrict__ ifb, float* __restrict__ IFc) {
  __shared__ float Xs[64 * 72];
  __shared__ float Ws[32 * 68];
  int tid = threadIdx.x;
  int r0 = blockIdx.x << 6;
  int nc = tid & 15;
  int rg = tid >> 4;
  int n0 = nc << 1;
  int sw = ((n0 >> 3) & 3) << 2;
  int sx = (rg & 3) << 2;

  float acc[4][2];
#pragma unroll
  for (int j = 0; j < 4; ++j) { acc[j][0] = 0.f; acc[j][1] = 0.f; }

  for (int k0 = 0; k0 < D_IN; k0 += 64) {
    __syncthreads();
#pragma unroll
    for (int i = 0; i < 4; ++i) {
      int fi = (i << 8) + tid;
      int row = fi >> 4, kk = (fi & 15) << 2;
      float4 v = *(const float4*)(X + (size_t)(r0 + row) * D_IN + k0 + kk);
      *(float4*)&Xs[row * 72 + (kk ^ (((row >> 2) & 3) << 2))] = v;
    }
#pragma unroll
    for (int i = 0; i < 2; ++i) {
      int fi = (i << 8) + tid;
      int row = fi >> 4, kk = (fi & 15) << 2;
      float4 v = *(const float4*)(ifw + (size_t)row * D_IN + k0 + kk);
      *(float4*)&Ws[row * 68 + (kk ^ (((row >> 3) & 3) << 2))] = v;
    }
    __syncthreads();
#pragma unroll
    for (int k4 = 0; k4 < 64; k4 += 4) {
      float4 w0 = *(const float4*)&Ws[n0 * 68 + (k4 ^ sw)];
      float4 w1 = *(const float4*)&Ws[(n0 + 1) * 68 + (k4 ^ sw)];
#pragma unroll
      for (int j = 0; j < 4; ++j) {
        float4 xv = *(const float4*)&Xs[((rg << 2) + j) * 72 + (k4 ^ sx)];
        acc[j][0] = fmaf(xv.x, w0.x, acc[j][0]);
        acc[j][0] = fmaf(xv.y, w0.y, acc[j][0]);
        acc[j][0] = fmaf(xv.z, w0.z, acc[j][0]);
        acc[j][0] = fmaf(xv.w, w0.w, acc[j][0]);
        acc[j][1] = fmaf(xv.x, w1.x, acc[j][1]);
        acc[j][1] = fmaf(xv.y, w1.y, acc[j][1]);
        acc[j][1] = fmaf(xv.z, w1.z, acc[j][1]);
        acc[j][1] = fmaf(xv.w, w1.w, acc[j][1]);
      }
    }
  }
  float b0 = ifb[n0], b1 = ifb[n0 + 1];
#pragma unroll
  for (int j = 0; j < 4; ++j) {
    int row = r0 + (rg << 2) + j;
    float2 st; st.x = acc[j][0] + b0; st.y = acc[j][1] + b1;
    *(float2*)(IFc + ((size_t)row << 5) + n0) = st;
  }
}

// -------------------------------------------------------------------------
// Parallel m-scan (associative (max,+) compose), 16 blocks x 256 threads.
// -------------------------------------------------------------------------
__global__ __launch_bounds__(256) void mscan(const float* __restrict__ IFc, float* __restrict__ M) {
  int h = blockIdx.x;
  int tid = threadIdx.x;
  int lane = tid & 63, wv = tid >> 6;
  int t0 = tid << 5;
  float F = 0.f, I = -1e30f;
#pragma unroll 8
  for (int u = 0; u < 32; ++u) {
    float2 v = *(const float2*)(IFc + ((size_t)(t0 + u) << 5) + (h << 1));
    I = fmaxf(I + v.y, v.x);
    F += v.y;
  }
#pragma unroll
  for (int d = 1; d < 64; d <<= 1) {
    float Fo = __shfl_up(F, d, 64);
    float Io = __shfl_up(I, d, 64);
    if (lane >= d) { I = fmaxf(Io + F, I); F = Fo + F; }
  }
  __shared__ float sF[4], sI[4];
  if (lane == 63) { sF[wv] = F; sI[wv] = I; }
  float Fe = __shfl_up(F, 1, 64);
  float Ie = __shfl_up(I, 1, 64);
  if (lane == 0) { Fe = 0.f; Ie = -1e30f; }
  __syncthreads();
  float Fp = 0.f, Ip = -1e30f;
  for (int w = 0; w < wv; ++w) { Ip = fmaxf(Ip + sF[w], sI[w]); Fp += sF[w]; }
  float Ft = Fp + Fe;
  float It = fmaxf(Ip + Fe, Ie);
  float m = fmaxf(Ft, It);
#pragma unroll 8
  for (int u = 0; u < 32; ++u) {
    float2 v = *(const float2*)(IFc + ((size_t)(t0 + u) << 5) + (h << 1));
    m = fmaxf(v.y + m, v.x);
    M[(size_t)(t0 + u) * NH + h] = m;
  }
}

// -------------------------------------------------------------------------
// D1: DC(f16) = sum_s g_s v_s k_s^T, DN = sum_s g_s k_s, DL.
// -------------------------------------------------------------------------
__global__ __launch_bounds__(256) void d1_dc(
    const _Float16* __restrict__ Ph, const float* __restrict__ IFc,
    const float* __restrict__ M,
    _Float16* __restrict__ DCh, float* __restrict__ DN, float* __restrict__ DL) {
  int c = blockIdx.x >> 4, h = blockIdx.x & 15;
  int t0 = c << 6, hb = 32 + (h << 8);
  int tid = threadIdx.x;
  __shared__ float Kl[64][65];
  __shared__ float Vl[64][65];
  __shared__ float gl[64];
#pragma unroll
  for (int i = 0; i < 2; ++i) {
    int fq = (i << 8) + tid;
    int s = fq >> 3, b8 = (fq & 7) << 3;
    const _Float16* row = Ph + (size_t)(t0 + s) * NPAD + hb;
    f16x8 kv = *(const f16x8*)(row + b8);
    f16x8 vv = *(const f16x8*)(row + 128 + b8);
#pragma unroll
    for (int j = 0; j < 8; ++j) {
      Kl[s][b8 + j] = (float)kv[j];
      Vl[s][b8 + j] = (float)vv[j];
    }
  }
  if (tid < 64) {
    float2 iff = *(const float2*)(IFc + ((size_t)(t0 + tid) << 5) + (h << 1));
    float iv = iff.x, fv = iff.y;
    float cs = fv;
#pragma unroll
    for (int dd = 1; dd < 64; dd <<= 1) {
      float o = __shfl_up(cs, dd, 64);
      cs += (tid >= dd) ? o : 0.f;
    }
    float cumL = __shfl(cs, 63, 64);
    float mL = M[(size_t)(t0 + 63) * NH + h];
    gl[tid] = __expf(cumL - cs + iv - mL);
    if (tid == 0) {
      float mstart = (c > 0) ? M[(size_t)(t0 - 1) * NH + h] : 0.f;
      DL[(c << 4) + h] = __expf(mstart + cumL - mL);
    }
  }
  __syncthreads();
  if (tid < 64) {
    float acc = 0.f;
#pragma unroll
    for (int s = 0; s < 64; ++s) acc = fmaf(gl[s], Kl[s][tid], acc);
    DN[((size_t)(c << 4) + h) * 64 + tid] = acc;
  }
  int a = tid & 63, bq = tid >> 6;
  float acc[16];
#pragma unroll
  for (int j = 0; j < 16; ++j) acc[j] = 0.f;
  for (int s = 0; s < 64; ++s) {
    float gv = gl[s] * Vl[s][a];
#pragma unroll
    for (int j = 0; j < 16; ++j) acc[j] = fmaf(gv, Kl[s][(bq << 4) + j], acc[j]);
  }
  size_t base = (((size_t)(c << 4) + h) << 12) + ((size_t)a << 6) + (bq << 4);
  f16x8 s0, s1;
#pragma unroll
  for (int j = 0; j < 8; ++j) { s0[j] = (_Float16)acc[j]; s1[j] = (_Float16)acc[8 + j]; }
  *(f16x8*)(DCh + base) = s0;
  *(f16x8*)(DCh + base + 8) = s1;
}

// -------------------------------------------------------------------------
// D2a: per (group, elem) affine aggregates over the group's 16 chunks.
// -------------------------------------------------------------------------
__global__ __launch_bounds__(256) void d2a(
    const _Float16* __restrict__ DCh, const float* __restrict__ DN,
    const float* __restrict__ DL,
    float* __restrict__ BgDC, float* __restrict__ BgDN, float* __restrict__ Ag) {
  int bid = blockIdx.x, tid = threadIdx.x;
  if (bid < 2048) {
    int linear = (bid << 8) + tid;
    int g = linear >> 16, e = linear & 65535;
    int h = e >> 12;
    float carry = 0.f, a = 1.f;
    size_t idx = (size_t)e + ((size_t)g << 4) * 65536;
    float v = (float)DCh[idx];
    for (int u = 0; u < GSZ; ++u) {
      float dl = DL[(((g << 4) + u) << 4) + h];
      float vn = (u < GSZ - 1) ? (float)DCh[idx + 65536] : 0.f;
      carry = fmaf(dl, carry, v);
      a *= dl;
      v = vn;
      idx += 65536;
    }
    BgDC[((size_t)g << 16) + e] = carry;
    if ((e & 4095) == 0) Ag[(g << 4) + h] = a;
  } else {
    int linear = ((bid - 2048) << 8) + tid;
    int g = linear >> 10, e = linear & 1023;
    int h = e >> 6;
    float carry = 0.f;
    size_t idx = (size_t)e + ((size_t)g << 4) * 1024;
    float v = DN[idx];
    for (int u = 0; u < GSZ; ++u) {
      float dl = DL[(((g << 4) + u) << 4) + h];
      float vn = (u < GSZ - 1) ? DN[idx + 1024] : 0.f;
      carry = fmaf(dl, carry, v);
      v = vn;
      idx += 1024;
    }
    BgDN[(g << 10) + e] = carry;
  }
}

// -------------------------------------------------------------------------
// D2c: inline exclusive group-prefix then in-place exclusive carries.
// -------------------------------------------------------------------------
__global__ __launch_bounds__(256) void d2c(
    _Float16* __restrict__ DCh, float* __restrict__ DN,
    const float* __restrict__ DL,
    const float* __restrict__ BgDC, const float* __restrict__ BgDN,
    const float* __restrict__ Ag) {
  int bid = blockIdx.x, tid = threadIdx.x;
  if (bid < 2048) {
    int linear = (bid << 8) + tid;
    int g = linear >> 16, e = linear & 65535;
    int h = e >> 12;
    float P = 0.f;
    for (int gp = 0; gp < g; ++gp)
      P = fmaf(Ag[(gp << 4) + h], P, BgDC[((size_t)gp << 16) + e]);
    float carry = P;
    size_t idx = (size_t)e + ((size_t)g << 4) * 65536;
    float v = (float)DCh[idx];
    for (int u = 0; u < GSZ; ++u) {
      float dl = DL[(((g << 4) + u) << 4) + h];
      float vn = (u < GSZ - 1) ? (float)DCh[idx + 65536] : 0.f;
      DCh[idx] = (_Float16)carry;
      carry = fmaf(dl, carry, v);
      v = vn;
      idx += 65536;
    }
  } else {
    int linear = ((bid - 2048) << 8) + tid;
    int g = linear >> 10, e = linear & 1023;
    int h = e >> 6;
    float P = 0.f;
    for (int gp = 0; gp < g; ++gp)
      P = fmaf(Ag[(gp << 4) + h], P, BgDN[(gp << 10) + e]);
    float carry = P;
    size_t idx = (size_t)e + ((size_t)g << 4) * 1024;
    float v = DN[idx];
    for (int u = 0; u < GSZ; ++u) {
      float dl = DL[(((g << 4) + u) << 4) + h];
      float vn = (u < GSZ - 1) ? DN[idx + 1024] : 0.f;
      DN[idx] = carry;
      carry = fmaf(dl, carry, v);
      v = vn;
      idx += 1024;
    }
  }
}

// -------------------------------------------------------------------------
// D3 (MFMA): per (chunk,head) outputs. 4 waves; wave owns 16-row band.
// QK^T, PV, Q·Cstart^T as 16x16x32 f16 MFMAs; gating in C/D layout
// (col=lane&15, row=(lane>>4)*4+r); rowsums in-register via shfl_xor.
// V transposed at staging (B-operand needs [a][s]); LDS stride 72 f16
// -> fragment reads 2-way bank-aliased (free, m136).
// -------------------------------------------------------------------------
__global__ __launch_bounds__(256) void d3_out(
    const _Float16* __restrict__ Ph, const float* __restrict__ IFc,
    const float* __restrict__ M,
    const _Float16* __restrict__ CS, const float* __restrict__ NS,
    float* __restrict__ out) {
  int c = blockIdx.x >> 4, h = blockIdx.x & 15;
  int t0 = c << 6, hb = 32 + (h << 8);
  int tid = threadIdx.x;
  int lane = tid & 63, wave = tid >> 6;
  __shared__ _Float16 Kh[64 * 72];
  __shared__ _Float16 Qh[64 * 72];
  __shared__ _Float16 Vt[64 * 72];   // Vt[a][s] = V[s][a]
  __shared__ _Float16 Ch[64 * 72];   // Ch[a][b] = Cstart[a][b]
  __shared__ _Float16 Oh[64 * 72];
  __shared__ _Float16 Pl[64 * 72];   // gated P, f16
  __shared__ float cf[64], il[64], ml[64], dl[64], nq[64], nsl[64];

#pragma unroll
  for (int i = 0; i < 2; ++i) {
    int fq = (i << 8) + tid;
    int s = fq >> 3, b8 = (fq & 7) << 3;
    const _Float16* row = Ph + (size_t)(t0 + s) * NPAD + hb;
    f16x8 kv = *(const f16x8*)(row + b8);
    f16x8 qv = *(const f16x8*)(row + 64 + b8);
    f16x8 vv = *(const f16x8*)(row + 128 + b8);
    f16x8 ov = *(const f16x8*)(row + 192 + b8);
    f16x8 cv = *(const f16x8*)(CS + ((((size_t)(c << 4)) + h) << 12) + ((size_t)s << 6) + b8);
    *(f16x8*)&Kh[s * 72 + b8] = kv;
    *(f16x8*)&Qh[s * 72 + b8] = qv;
    *(f16x8*)&Oh[s * 72 + b8] = ov;
    *(f16x8*)&Ch[s * 72 + b8] = cv;
#pragma unroll
    for (int j = 0; j < 8; ++j) Vt[(b8 + j) * 72 + s] = vv[j];
  }
  __syncthreads();

  float iv = 0.f, mt = 0.f, cs = 0.f;
  if (tid < 64) {
    float2 iff = *(const float2*)(IFc + ((size_t)(t0 + tid) << 5) + (h << 1));
    iv = iff.x;
    float fv = iff.y;
    mt = M[(size_t)(t0 + tid) * NH + h];
    nsl[tid] = NS[((size_t)(c << 4) + h) * 64 + tid];
    cs = fv;
#pragma unroll
    for (int dd = 1; dd < 64; dd <<= 1) {
      float o = __shfl_up(cs, dd, 64);
      cs += (tid >= dd) ? o : 0.f;
    }
  }
  __syncthreads();
  if (tid < 64) {
    cf[tid] = cs; il[tid] = iv; ml[tid] = mt;
    float mstart = (c > 0) ? M[(size_t)(t0 - 1) * NH + h] : 0.f;
    dl[tid] = __expf(mstart + cs - mt);
    float acc = 0.f;
#pragma unroll
    for (int b = 0; b < 64; ++b) acc = fmaf(nsl[b], (float)Qh[tid * 72 + b], acc);
    nq[tid] = acc;
  }
  __syncthreads();

  int band = wave << 4;
  int arow = lane & 15;
  int kq = (lane >> 4) << 3;
  int crow = (lane >> 4) << 2;

  f16x8 aq0 = *(const f16x8*)&Qh[(band + arow) * 72 + kq];
  f16x8 aq1 = *(const f16x8*)&Qh[(band + arow) * 72 + 32 + kq];

  f32x4 S[4];
  f32x4 zero = {0.f, 0.f, 0.f, 0.f};
#pragma unroll
  for (int n = 0; n < 4; ++n) S[n] = zero;
#pragma unroll
  for (int n = 0; n < 4; ++n) {
    f16x8 b0 = *(const f16x8*)&Kh[((n << 4) + arow) * 72 + kq];
    f16x8 b1 = *(const f16x8*)&Kh[((n << 4) + arow) * 72 + 32 + kq];
    S[n] = __builtin_amdgcn_mfma_f32_16x16x32_f16(aq0, b0, S[n], 0, 0, 0);
    S[n] = __builtin_amdgcn_mfma_f32_16x16x32_f16(aq1, b1, S[n], 0, 0, 0);
  }

  // gating + in-register rowsums + P->f16 LDS
  float cft[4], mlt[4];
#pragma unroll
  for (int r = 0; r < 4; ++r) {
    int t = band + crow + r;
    cft[r] = cf[t]; mlt[r] = ml[t];
  }
  float rsum[4] = {0.f, 0.f, 0.f, 0.f};
#pragma unroll
  for (int n = 0; n < 4; ++n) {
    int s = (n << 4) + arow;
    float cfs = cf[s], ils = il[s];
#pragma unroll
    for (int r = 0; r < 4; ++r) {
      int t = band + crow + r;
      float w = (s <= t) ? __expf(cft[r] - cfs + ils - mlt[r]) : 0.f;
      float p = S[n][r] * w;
      rsum[r] += p;
      Pl[t * 72 + s] = (_Float16)p;
    }
  }
#pragma unroll
  for (int r = 0; r < 4; ++r) {
    float p = rsum[r];
    p += __shfl_xor(p, 1);
    p += __shfl_xor(p, 2);
    p += __shfl_xor(p, 4);
    p += __shfl_xor(p, 8);
    rsum[r] = p;
  }
  __syncthreads();   // Pl visible

  f16x8 ap0 = *(const f16x8*)&Pl[(band + arow) * 72 + kq];
  f16x8 ap1 = *(const f16x8*)&Pl[(band + arow) * 72 + 32 + kq];
  f32x4 H[4], I[4];
#pragma unroll
  for (int n = 0; n < 4; ++n) { H[n] = zero; I[n] = zero; }
#pragma unroll
  for (int n = 0; n < 4; ++n) {
    f16x8 bv0 = *(const f16x8*)&Vt[((n << 4) + arow) * 72 + kq];
    f16x8 bv1 = *(const f16x8*)&Vt[((n << 4) + arow) * 72 + 32 + kq];
    H[n] = __builtin_amdgcn_mfma_f32_16x16x32_f16(ap0, bv0, H[n], 0, 0, 0);
    H[n] = __builtin_amdgcn_mfma_f32_16x16x32_f16(ap1, bv1, H[n], 0, 0, 0);
    f16x8 bc0 = *(const f16x8*)&Ch[((n << 4) + arow) * 72 + kq];
    f16x8 bc1 = *(const f16x8*)&Ch[((n << 4) + arow) * 72 + 32 + kq];
    I[n] = __builtin_amdgcn_mfma_f32_16x16x32_f16(aq0, bc0, I[n], 0, 0, 0);
    I[n] = __builtin_amdgcn_mfma_f32_16x16x32_f16(aq1, bc1, I[n], 0, 0, 0);
  }

#pragma unroll
  for (int r = 0; r < 4; ++r) {
    int t = band + crow + r;
    float dt = dl[t];
    float dn = fmaf(dt, nq[t], rsum[r]);
    float rinv = 1.f / fmaxf(fabsf(dn), 1.f);
    float* orow = out + (size_t)(t0 + t) * 1024 + (h << 6);
#pragma unroll
    for (int n = 0; n < 4; ++n) {
      int a = (n << 4) + arow;
      float o = 1.f / (1.f + __expf(-(float)Oh[t * 72 + a]));
      orow[a] = o * (fmaf(dt, I[n][r], H[n][r]) * rinv);
    }
  }
}

// -------------------------------------------------------------------------
extern "C" void kernel_launch(void* const* d_in, const int* in_sizes, int n_in,
                              void* d_out, int out_size, void* d_ws, size_t ws_size,
                              hipStream_t stream) {
  const float* xs   = (const float*)d_in[0];
  const float* ifw  = (const float*)d_in[1];
  const float* ow   = (const float*)d_in[2];
  const float* kqw  = (const float*)d_in[3];
  const float* vw   = (const float*)d_in[4];
  const float* ifb  = (const float*)d_in[5];
  const float* ob   = (const float*)d_in[6];
  const float* kvqb = (const float*)d_in[7];
  float* ws   = (float*)d_ws;
  _Float16* Wph = (_Float16*)(ws + OFF_WP);
  float* BgDC = ws + OFF_BG;
  float* BgDN = BgDC + (size_t)NGRP * 65536;
  float* Ag   = BgDN + (size_t)NGRP * 1024;
  float* bias = ws + OFF_BIAS;
  _Float16* Phm = (_Float16*)(ws + OFF_P);
  float* Mm   = ws + OFF_M;
  _Float16* DCh = (_Float16*)(ws + OFF_DC);
  _Float16* Xh  = (_Float16*)(ws + OFF_DC);  // alias: consumed by gemm before d1 writes DCh
  float* DN   = ws + OFF_DN;
  float* DL   = ws + OFF_DL;
  float* IFc  = ws + OFF_IF;
  float* outp = (float*)d_out;

  hipLaunchKernelGGL(pack_conv, dim3(NPACK + NCONV), dim3(256), 0, stream,
                     ifw, ow, kqw, vw, ifb, ob, kvqb, Wph, bias, xs, Xh);
  hipLaunchKernelGGL(gemm_f16, dim3(33 * 64), dim3(256), 0, stream,
                     Xh, Wph, bias, Phm);
  hipLaunchKernelGGL(gemm_if, dim3(T_LEN / 64), dim3(256), 0, stream, xs, ifw, ifb, IFc);
  hipLaunchKernelGGL(mscan, dim3(NH), dim3(256), 0, stream, IFc, Mm);
  hipLaunchKernelGGL(d1_dc, dim3(NCH * NH), dim3(256), 0, stream, Phm, IFc, Mm, DCh, DN, DL);
  hipLaunchKernelGGL(d2a, dim3(2080), dim3(256), 0, stream, DCh, DN, DL, BgDC, BgDN, Ag);
  hipLaunchKernelGGL(d2c, dim3(2080), dim3(256), 0, stream, DCh, DN, DL, BgDC, BgDN, Ag);
  hipLaunchKernelGGL(d3_out, dim3(NCH * NH), dim3(256), 0, stream, Phm, IFc, Mm, DCh, DN, outp);
}